// Round 7
// baseline (337.380 us; speedup 1.0000x reference)
//
#include <hip/hip_runtime.h>
#include <hip/hip_bf16.h>

#define NATOMS 10000
#define NEDGES 320000
#define H 128
#define NRBF 50
#define NELEM (NATOMS * H)
#define NT 4096

typedef unsigned short u16;
typedef unsigned int u32;
typedef __attribute__((ext_vector_type(8))) short short8;
typedef __attribute__((ext_vector_type(4))) float float4v;
typedef __attribute__((ext_vector_type(4))) unsigned int uint4v;

__device__ __forceinline__ float bfu(u16 u) { return __uint_as_float(((u32)u) << 16); }
__device__ __forceinline__ u16 bf16r(float v) {   // RNE
    u32 u = __float_as_uint(v);
    return (u16)((u + 0x7FFFu + ((u >> 16) & 1u)) >> 16);
}
__device__ __forceinline__ float ldf(const void* p, int i, int bf) {
    return bf ? bfu(((const u16*)p)[i]) : ((const float*)p)[i];
}
__device__ __forceinline__ float silu_f(float v) { return v / (1.f + __expf(-v)); }
// inline dtype detect (proven logic r3-r17): means[49]==1.0 -> bf16 word24 hi = 0x3F80
__device__ __forceinline__ int bfflag(const void* means) {
    return ((((const u32*)means)[24] >> 16) == 0x3F80u) ? 1 : 0;
}

// ---- R24: paired-table store. T2 layout: uint2 per (pair p, lane l):
//   .x = {T[p][2l], T[p][2l+1]}  .y = {T[p+1][2l], T[p+1][2l+1]}
// Row n's value at col f lands in pair n slot 0 and pair n-1 slot 1.
__device__ __forceinline__ void st2(u16* __restrict__ T2, int n, int f, u16 v) {
    int q = (f >> 1) * 4 + (f & 1);
    T2[n * 256 + q] = v;
    if (n > 0) T2[(n - 1) * 256 + q + 2] = v;
}

// ---- embed: x0 fp32 + bf16 mirror (proven scalar form); zeroes deg/cnt ----
__global__ __launch_bounds__(256) void k_embed(const int* __restrict__ z, const void* emb,
                                               const void* means,
                                               float* __restrict__ x0, u16* __restrict__ xh,
                                               int* __restrict__ degz) {
    int bf = bfflag(means);
    int i = blockIdx.x * 256 + threadIdx.x;
    if (i < 20480) degz[i] = 0;
    if (i < NELEM) {
        int n = i >> 7, f = i & 127;
        float v = ldf(emb, z[n] * H + f, bf);
        x0[i] = v;
        xh[i] = bf16r(v);
    }
}

// ---- bf16 LDS weight staging for MFMA: row stride 136 u16 (68 u32).
// R23 proven: 16B vector loads + 16B LDS writes (row byte stride 272 = 17*16).
__device__ __forceinline__ void stage_w16(const void* W, int woff, int wstride,
                                          u16* sW, int tid, int nthr, int bf) {
    u32* sW32 = (u32*)sW;
    if (bf) {
        const uint4v* W4 = (const uint4v*)W;     // 8 bf16 per uint4
        for (int i = tid; i < 128 * 16; i += nthr) {
            int f2 = i >> 4, k4 = i & 15;
            uint4v v = W4[((woff + f2 * wstride) >> 3) + k4];
            *(uint4v*)&sW32[f2 * 68 + k4 * 4] = v;
        }
    } else {
        const float4* Wf4 = (const float4*)W;
        for (int i = tid; i < 128 * 16; i += nthr) {
            int f2 = i >> 4, k4 = i & 15;
            int base = ((woff + f2 * wstride) >> 2) + k4 * 2;
            float4 a = Wf4[base], b = Wf4[base + 1];
            uint4v v;
            v.x = (u32)bf16r(a.x) | ((u32)bf16r(a.y) << 16);
            v.y = (u32)bf16r(a.z) | ((u32)bf16r(a.w) << 16);
            v.z = (u32)bf16r(b.x) | ((u32)bf16r(b.y) << 16);
            v.w = (u32)bf16r(b.z) | ((u32)bf16r(b.w) << 16);
            *(uint4v*)&sW32[f2 * 68 + k4 * 4] = v;
        }
    }
}

// ---- MFMA node GEMM (R23 proven):
//   x += silu(in@W2.T+b2)@Wl.T+bl ; if W1n: hb = bf16(x_new @ W1n.T) ----
__global__ __launch_bounds__(256) void k_mfma_lin(const u32* __restrict__ in,
                                                  const void* W2, int w2off,
                                                  const void* B2, int b2off,
                                                  const void* Wl, int wloff,
                                                  const void* Bl, int bloff,
                                                  const void* W1n, int w1noff,
                                                  float* x, u16* __restrict__ hb,
                                                  const void* means,
                                                  void* outp) {
    __shared__ u16 sW2[128 * 136];
    __shared__ u16 sWl[128 * 136];
    __shared__ u16 sW1[128 * 136];
    __shared__ u16 sA[4][16 * 136];
    __shared__ float sB2v[128], sBlv[128];
    int tid = threadIdx.x;
    int bf = bfflag(means);
    stage_w16(W2, w2off, H, sW2, tid, 256, bf);
    stage_w16(Wl, wloff, H, sWl, tid, 256, bf);
    if (W1n) stage_w16(W1n, w1noff, H, sW1, tid, 256, bf);
    if (tid < 128) {
        sB2v[tid] = ldf(B2, b2off + tid, bf);
        sBlv[tid] = ldf(Bl, bloff + tid, bf);
    }
    __syncthreads();
    int w = tid >> 6, lane = tid & 63;
    int quad = lane >> 4, l16 = lane & 15;
    u16* myA = sA[w];
    u32* myA32 = (u32*)myA;
    for (int tile = blockIdx.x * 4 + w; tile < NATOMS / 16; tile += gridDim.x * 4) {
        int abase = tile * 16;
        const u32* in2 = in + (size_t)abase * 64;
        #pragma unroll 4
        for (int j = 0; j < 16; ++j)
            myA32[j * 68 + lane] = in2[j * 64 + lane];
        __asm__ volatile("s_waitcnt lgkmcnt(0)" ::: "memory");
        short8 af0 = *(const short8*)&myA[l16 * 136 +   0 + quad * 8];
        short8 af1 = *(const short8*)&myA[l16 * 136 +  32 + quad * 8];
        short8 af2 = *(const short8*)&myA[l16 * 136 +  64 + quad * 8];
        short8 af3 = *(const short8*)&myA[l16 * 136 +  96 + quad * 8];
        // GEMM 1: myA <- bf16(silu(in @ W2.T + b2))
        #pragma unroll 1
        for (int nt = 0; nt < 8; ++nt) {
            const u16* wrow = &sW2[(nt * 16 + l16) * 136];
            short8 b0 = *(const short8*)&wrow[0  + quad * 8];
            short8 b1 = *(const short8*)&wrow[32 + quad * 8];
            short8 b2 = *(const short8*)&wrow[64 + quad * 8];
            short8 b3 = *(const short8*)&wrow[96 + quad * 8];
            float4v acc = {0.f, 0.f, 0.f, 0.f};
            acc = __builtin_amdgcn_mfma_f32_16x16x32_bf16(af0, b0, acc, 0, 0, 0);
            acc = __builtin_amdgcn_mfma_f32_16x16x32_bf16(af1, b1, acc, 0, 0, 0);
            acc = __builtin_amdgcn_mfma_f32_16x16x32_bf16(af2, b2, acc, 0, 0, 0);
            acc = __builtin_amdgcn_mfma_f32_16x16x32_bf16(af3, b3, acc, 0, 0, 0);
            int col = nt * 16 + l16;
            float bias = sB2v[col];
            myA[(quad * 4 + 0) * 136 + col] = bf16r(silu_f(acc[0] + bias));
            myA[(quad * 4 + 1) * 136 + col] = bf16r(silu_f(acc[1] + bias));
            myA[(quad * 4 + 2) * 136 + col] = bf16r(silu_f(acc[2] + bias));
            myA[(quad * 4 + 3) * 136 + col] = bf16r(silu_f(acc[3] + bias));
        }
        __asm__ volatile("s_waitcnt lgkmcnt(0)" ::: "memory");
        short8 t0 = *(const short8*)&myA[l16 * 136 +   0 + quad * 8];
        short8 t1 = *(const short8*)&myA[l16 * 136 +  32 + quad * 8];
        short8 t2 = *(const short8*)&myA[l16 * 136 +  64 + quad * 8];
        short8 t3 = *(const short8*)&myA[l16 * 136 +  96 + quad * 8];
        // GEMM 2: x += t @ Wl.T + bl ; stash bf16(x_new) back to myA for GEMM 3
        #pragma unroll 1
        for (int nt = 0; nt < 8; ++nt) {
            const u16* wrow = &sWl[(nt * 16 + l16) * 136];
            short8 b0 = *(const short8*)&wrow[0  + quad * 8];
            short8 b1 = *(const short8*)&wrow[32 + quad * 8];
            short8 b2 = *(const short8*)&wrow[64 + quad * 8];
            short8 b3 = *(const short8*)&wrow[96 + quad * 8];
            int col = nt * 16 + l16;
            float bias = sBlv[col];
            float4v acc;
            acc[0] = x[(size_t)(abase + quad * 4 + 0) * H + col] + bias;
            acc[1] = x[(size_t)(abase + quad * 4 + 1) * H + col] + bias;
            acc[2] = x[(size_t)(abase + quad * 4 + 2) * H + col] + bias;
            acc[3] = x[(size_t)(abase + quad * 4 + 3) * H + col] + bias;
            acc = __builtin_amdgcn_mfma_f32_16x16x32_bf16(t0, b0, acc, 0, 0, 0);
            acc = __builtin_amdgcn_mfma_f32_16x16x32_bf16(t1, b1, acc, 0, 0, 0);
            acc = __builtin_amdgcn_mfma_f32_16x16x32_bf16(t2, b2, acc, 0, 0, 0);
            acc = __builtin_amdgcn_mfma_f32_16x16x32_bf16(t3, b3, acc, 0, 0, 0);
            #pragma unroll
            for (int r = 0; r < 4; ++r) {
                size_t idx = (size_t)(abase + quad * 4 + r) * H + col;
                x[idx] = acc[r];
                myA[(quad * 4 + r) * 136 + col] = bf16r(acc[r]);
                if (outp) {
                    if (bf) ((u16*)outp)[idx] = bf16r(acc[r]);
                    else    ((float*)outp)[idx] = acc[r];
                }
            }
        }
        // GEMM 3 (fused next-layer lin1): hb = bf16(x_new @ W1n.T), no bias
        if (W1n) {
            __asm__ volatile("s_waitcnt lgkmcnt(0)" ::: "memory");
            short8 h0 = *(const short8*)&myA[l16 * 136 +   0 + quad * 8];
            short8 h1 = *(const short8*)&myA[l16 * 136 +  32 + quad * 8];
            short8 h2 = *(const short8*)&myA[l16 * 136 +  64 + quad * 8];
            short8 h3 = *(const short8*)&myA[l16 * 136 +  96 + quad * 8];
            #pragma unroll 1
            for (int nt = 0; nt < 8; ++nt) {
                const u16* wrow = &sW1[(nt * 16 + l16) * 136];
                short8 b0 = *(const short8*)&wrow[0  + quad * 8];
                short8 b1 = *(const short8*)&wrow[32 + quad * 8];
                short8 b2 = *(const short8*)&wrow[64 + quad * 8];
                short8 b3 = *(const short8*)&wrow[96 + quad * 8];
                float4v acc = {0.f, 0.f, 0.f, 0.f};
                acc = __builtin_amdgcn_mfma_f32_16x16x32_bf16(h0, b0, acc, 0, 0, 0);
                acc = __builtin_amdgcn_mfma_f32_16x16x32_bf16(h1, b1, acc, 0, 0, 0);
                acc = __builtin_amdgcn_mfma_f32_16x16x32_bf16(h2, b2, acc, 0, 0, 0);
                acc = __builtin_amdgcn_mfma_f32_16x16x32_bf16(h3, b3, acc, 0, 0, 0);
                int col = nt * 16 + l16;
                hb[(size_t)(abase + quad * 4 + 0) * H + col] = bf16r(acc[0]);
                hb[(size_t)(abase + quad * 4 + 1) * H + col] = bf16r(acc[1]);
                hb[(size_t)(abase + quad * 4 + 2) * H + col] = bf16r(acc[2]);
                hb[(size_t)(abase + quad * 4 + 3) * H + col] = bf16r(acc[3]);
            }
        }
    }
}

// ---- MFMA NE combine (R23 proven); also hb = bf16(x @ l1w0.T) ----
__global__ __launch_bounds__(256) void k_mfma_comb(const float* in0, const u32* __restrict__ in1,
                                                   const void* W, const void* B,
                                                   const void* W1,
                                                   float* x, u16* __restrict__ hb,
                                                   const void* means) {
    __shared__ u16 sWa[128 * 136];
    __shared__ u16 sWb[128 * 136];
    __shared__ u16 sW1[128 * 136];
    __shared__ u16 sA[4][16 * 136];
    __shared__ float sBv[128];
    int tid = threadIdx.x;
    int bf = bfflag(means);
    stage_w16(W, 0,   256, sWa, tid, 256, bf);
    stage_w16(W, 128, 256, sWb, tid, 256, bf);
    stage_w16(W1, 0, H, sW1, tid, 256, bf);
    if (tid < 128) sBv[tid] = ldf(B, tid, bf);
    __syncthreads();
    int w = tid >> 6, lane = tid & 63;
    int quad = lane >> 4, l16 = lane & 15;
    u16* myA = sA[w];
    u32* myA32 = (u32*)myA;
    for (int tile = blockIdx.x * 4 + w; tile < NATOMS / 16; tile += gridDim.x * 4) {
        int abase = tile * 16;
        const float2* i0 = (const float2*)in0 + (size_t)abase * 64;
        const u32* i1 = in1 + (size_t)abase * 64;
        #pragma unroll 4
        for (int j = 0; j < 16; ++j) {
            float2 v = i0[j * 64 + lane];
            myA32[j * 68 + lane] = (u32)bf16r(v.x) | ((u32)bf16r(v.y) << 16);
        }
        __asm__ volatile("s_waitcnt lgkmcnt(0)" ::: "memory");
        short8 af0 = *(const short8*)&myA[l16 * 136 +   0 + quad * 8];
        short8 af1 = *(const short8*)&myA[l16 * 136 +  32 + quad * 8];
        short8 af2 = *(const short8*)&myA[l16 * 136 +  64 + quad * 8];
        short8 af3 = *(const short8*)&myA[l16 * 136 +  96 + quad * 8];
        #pragma unroll 4
        for (int j = 0; j < 16; ++j)
            myA32[j * 68 + lane] = i1[j * 64 + lane];
        __asm__ volatile("s_waitcnt lgkmcnt(0)" ::: "memory");
        short8 ag0 = *(const short8*)&myA[l16 * 136 +   0 + quad * 8];
        short8 ag1 = *(const short8*)&myA[l16 * 136 +  32 + quad * 8];
        short8 ag2 = *(const short8*)&myA[l16 * 136 +  64 + quad * 8];
        short8 ag3 = *(const short8*)&myA[l16 * 136 +  96 + quad * 8];
        #pragma unroll 1
        for (int nt = 0; nt < 8; ++nt) {
            const u16* wra = &sWa[(nt * 16 + l16) * 136];
            const u16* wrb = &sWb[(nt * 16 + l16) * 136];
            int col = nt * 16 + l16;
            float bias = sBv[col];
            float4v acc = {bias, bias, bias, bias};
            acc = __builtin_amdgcn_mfma_f32_16x16x32_bf16(af0, *(const short8*)&wra[0  + quad * 8], acc, 0, 0, 0);
            acc = __builtin_amdgcn_mfma_f32_16x16x32_bf16(af1, *(const short8*)&wra[32 + quad * 8], acc, 0, 0, 0);
            acc = __builtin_amdgcn_mfma_f32_16x16x32_bf16(af2, *(const short8*)&wra[64 + quad * 8], acc, 0, 0, 0);
            acc = __builtin_amdgcn_mfma_f32_16x16x32_bf16(af3, *(const short8*)&wra[96 + quad * 8], acc, 0, 0, 0);
            acc = __builtin_amdgcn_mfma_f32_16x16x32_bf16(ag0, *(const short8*)&wrb[0  + quad * 8], acc, 0, 0, 0);
            acc = __builtin_amdgcn_mfma_f32_16x16x32_bf16(ag1, *(const short8*)&wrb[32 + quad * 8], acc, 0, 0, 0);
            acc = __builtin_amdgcn_mfma_f32_16x16x32_bf16(ag2, *(const short8*)&wrb[64 + quad * 8], acc, 0, 0, 0);
            acc = __builtin_amdgcn_mfma_f32_16x16x32_bf16(ag3, *(const short8*)&wrb[96 + quad * 8], acc, 0, 0, 0);
            #pragma unroll
            for (int r = 0; r < 4; ++r) {
                x[(size_t)(abase + quad * 4 + r) * H + col] = acc[r];
                myA[(quad * 4 + r) * 136 + col] = bf16r(acc[r]);
            }
        }
        // fused layer-0 lin1: hb = bf16(x @ l1w0.T)
        __asm__ volatile("s_waitcnt lgkmcnt(0)" ::: "memory");
        short8 h0 = *(const short8*)&myA[l16 * 136 +   0 + quad * 8];
        short8 h1 = *(const short8*)&myA[l16 * 136 +  32 + quad * 8];
        short8 h2 = *(const short8*)&myA[l16 * 136 +  64 + quad * 8];
        short8 h3 = *(const short8*)&myA[l16 * 136 +  96 + quad * 8];
        #pragma unroll 1
        for (int nt = 0; nt < 8; ++nt) {
            const u16* wrow = &sW1[(nt * 16 + l16) * 136];
            short8 b0 = *(const short8*)&wrow[0  + quad * 8];
            short8 b1 = *(const short8*)&wrow[32 + quad * 8];
            short8 b2 = *(const short8*)&wrow[64 + quad * 8];
            short8 b3 = *(const short8*)&wrow[96 + quad * 8];
            float4v acc = {0.f, 0.f, 0.f, 0.f};
            acc = __builtin_amdgcn_mfma_f32_16x16x32_bf16(h0, b0, acc, 0, 0, 0);
            acc = __builtin_amdgcn_mfma_f32_16x16x32_bf16(h1, b1, acc, 0, 0, 0);
            acc = __builtin_amdgcn_mfma_f32_16x16x32_bf16(h2, b2, acc, 0, 0, 0);
            acc = __builtin_amdgcn_mfma_f32_16x16x32_bf16(h3, b3, acc, 0, 0, 0);
            int col = nt * 16 + l16;
            hb[(size_t)(abase + quad * 4 + 0) * H + col] = bf16r(acc[0]);
            hb[(size_t)(abase + quad * 4 + 1) * H + col] = bf16r(acc[1]);
            hb[(size_t)(abase + quad * 4 + 2) * H + col] = bf16r(acc[2]);
            hb[(size_t)(abase + quad * 4 + 3) * H + col] = bf16r(acc[3]);
        }
    }
}

// ---- all 4 tables in one launch, R24 paired layout (st2 double-store).
//      t=0..2 filter tables, t=3 NE table ----
__global__ __launch_bounds__(1024) void k_ft4(const void* means, const void* betas,
                                              const void* W0s, const void* B0s,
                                              const void* W1s, const void* B1s,
                                              const void* Wne, const void* Bne,
                                              u16* __restrict__ ftT2,
                                              u16* __restrict__ Tne2) {
    __shared__ float sW0[H * 53];
    __shared__ u16 sW1b[128 * 136];
    __shared__ u16 sA16[16 * 136];
    __shared__ float sR[16][56];
    __shared__ float sM[NRBF], sBe[NRBF], sB1v[128], sC[16];
    int tid = threadIdx.x;
    int bf = bfflag(means);
    int t = blockIdx.x >> 8;                 // 0..2 = layer filter, 3 = NE table
    int bb = blockIdx.x & 255;
    int ne = (t == 3);
    const void* W0 = ne ? Wne : W0s;
    int w0off = ne ? 0 : t * H * NRBF;
    u16* T2 = ne ? Tne2 : (ftT2 + (size_t)t * NT * 256);
    if (!ne) stage_w16(W1s, t * H * H, H, sW1b, tid, 1024, bf);
    for (int i = tid; i < H * NRBF; i += 1024) {
        int f2 = i / NRBF, k = i - f2 * NRBF;
        sW0[f2 * 53 + k] = ldf(W0, w0off + i, bf);
    }
    if (tid < NRBF) { sM[tid] = ldf(means, tid, bf); sBe[tid] = ldf(betas, tid, bf); }
    if (tid < 128) sB1v[tid] = ne ? 0.f : ldf(B1s, t * H + tid, bf);
    __syncthreads();
    int g = tid >> 7, f = tid & 127;
    float b0r = ne ? ldf(Bne, f, bf) : ldf(B0s, t * H + f, bf);
    int base = bb * 16;
    int n0 = base + 2 * g, n1 = n0 + 1;
    float wv0 = (float)n0 * (5.0f / (NT - 1));
    float wv1 = (float)n1 * (5.0f / (NT - 1));
    if (f < NRBF) {
        float tt = expf(-wv0) - sM[f];
        sR[2 * g][f] = expf(-sBe[f] * tt * tt);
    } else if (f >= 64 && f < 64 + NRBF) {
        float tt = expf(-wv1) - sM[f - 64];
        sR[2 * g + 1][f - 64] = expf(-sBe[f - 64] * tt * tt);
    }
    __syncthreads();
    float c0 = 0.5f * (cosf(wv0 * 0.62831853071795864f) + 1.f); if (!(wv0 < 5.f)) c0 = 0.f;
    float c1 = 0.5f * (cosf(wv1 * 0.62831853071795864f) + 1.f); if (!(wv1 < 5.f)) c1 = 0.f;
    if (f == 0) { sC[2 * g] = c0; sC[2 * g + 1] = c1; }
    float s0 = 0.f, s1 = 0.f;
    #pragma unroll
    for (int k = 0; k < NRBF; ++k) {
        float wk = sW0[f * 53 + k];
        s0 = fmaf(wk, sR[2 * g][k], s0);
        s1 = fmaf(wk, sR[2 * g + 1][k], s1);
    }
    if (ne) {   // NE table: T = (c*acc + b)*c — block-uniform branch, safe return
        st2(T2, n0, f, bf16r(fmaf(c0, s0, b0r) * c0));
        st2(T2, n1, f, bf16r(fmaf(c1, s1, b0r) * c1));
        return;
    }
    sA16[(2 * g) * 136 + f]     = bf16r(silu_f(fmaf(c0, s0, b0r)));
    sA16[(2 * g + 1) * 136 + f] = bf16r(silu_f(fmaf(c1, s1, b0r)));
    __syncthreads();
    int w = tid >> 6;
    if (w < 8) {
        int lane = tid & 63;
        int quad = lane >> 4, l16 = lane & 15;
        short8 a0 = *(const short8*)&sA16[l16 * 136 +   0 + quad * 8];
        short8 a1 = *(const short8*)&sA16[l16 * 136 +  32 + quad * 8];
        short8 a2 = *(const short8*)&sA16[l16 * 136 +  64 + quad * 8];
        short8 a3 = *(const short8*)&sA16[l16 * 136 +  96 + quad * 8];
        const u16* wrow = &sW1b[(w * 16 + l16) * 136];
        short8 b0 = *(const short8*)&wrow[0  + quad * 8];
        short8 b1 = *(const short8*)&wrow[32 + quad * 8];
        short8 b2 = *(const short8*)&wrow[64 + quad * 8];
        short8 b3 = *(const short8*)&wrow[96 + quad * 8];
        float4v acc = {0.f, 0.f, 0.f, 0.f};
        acc = __builtin_amdgcn_mfma_f32_16x16x32_bf16(a0, b0, acc, 0, 0, 0);
        acc = __builtin_amdgcn_mfma_f32_16x16x32_bf16(a1, b1, acc, 0, 0, 0);
        acc = __builtin_amdgcn_mfma_f32_16x16x32_bf16(a2, b2, acc, 0, 0, 0);
        acc = __builtin_amdgcn_mfma_f32_16x16x32_bf16(a3, b3, acc, 0, 0, 0);
        int col = w * 16 + l16;
        float bias = sB1v[col];
        #pragma unroll
        for (int r = 0; r < 4; ++r) {
            int row = quad * 4 + r;
            st2(T2, base + row, col, bf16r((acc[r] + bias) * sC[row]));
        }
    }
}

// ---- counting sort by src (proven) ----
__global__ __launch_bounds__(256) void k_hist(const int* __restrict__ src, int* __restrict__ deg) {
    int e = blockIdx.x * 256 + threadIdx.x;
    if (e < NEDGES) atomicAdd(&deg[src[e]], 1);
}

// ---- R20: shuffle-based exclusive scan, 3 barriers.
__global__ __launch_bounds__(1024) void k_scan(const int* __restrict__ deg, int* __restrict__ rs) {
    __shared__ int wsum[16];
    int tid = threadIdx.x;
    int lane = tid & 63, w = tid >> 6;
    int d[10];
    int tot = 0;
    int base_i = tid * 10;
    if (tid < 1000) {
        #pragma unroll
        for (int j = 0; j < 10; ++j) d[j] = deg[base_i + j];
        #pragma unroll
        for (int j = 0; j < 10; ++j) { int v = d[j]; d[j] = tot; tot += v; }
    }
    int inc = tot;
    #pragma unroll
    for (int off = 1; off < 64; off <<= 1) {
        int n = __shfl_up(inc, off, 64);
        if (lane >= off) inc += n;
    }
    if (lane == 63) wsum[w] = inc;
    __syncthreads();
    if (w == 0) {
        int v = (lane < 16) ? wsum[lane] : 0;
        int vinc = v;
        #pragma unroll
        for (int off = 1; off < 16; off <<= 1) {
            int n = __shfl_up(vinc, off, 64);
            if (lane >= off) vinc += n;
        }
        if (lane < 16) wsum[lane] = vinc - v;   // exclusive wave offsets
    }
    __syncthreads();
    if (tid < 1000) {
        int base = wsum[w] + (inc - tot);
        #pragma unroll
        for (int j = 0; j < 10; ++j) rs[base_i + j] = base + d[j];
    }
}

// ---- R21: CSR edge data — one uint2 {dst, ew_scaled_bits} per edge ----
__global__ __launch_bounds__(256) void k_scatter_perm(const int* __restrict__ src,
                                                      const int* __restrict__ dst,
                                                      const void* ew, const void* means,
                                                      const int* __restrict__ rs,
                                                      int* __restrict__ cnt,
                                                      uint2* __restrict__ ed) {
    int bf = bfflag(means);
    int e = blockIdx.x * 256 + threadIdx.x;
    if (e < NEDGES) {
        int s = src[e];
        int p = rs[s] + atomicAdd(&cnt[s], 1);
        float u = ldf(ew, e, bf) * ((float)(NT - 1) / 5.0f);   // pre-scaled
        ed[p] = make_uint2((u32)dst[e], __float_as_uint(u));
    }
}

// ---- R24: GATHER with paired table — 2 data loads/edge/lane (was 3).
#define GEV(i) \
    uint2 ed##i = ed[e + i]; \
    int d##i = (int)ed##i.x; float u##i = __uint_as_float(ed##i.y); \
    int ix##i = min((int)u##i, NT - 2); float fr##i = u##i - (float)ix##i; \
    uint2 tt##i = Tb2[(size_t)ix##i * 64 + lane]; \
    u32 h##i = vh[d##i * 64 + lane]; \
    float vx##i = fmaf(fr##i, bfu((u16)(tt##i.y & 0xffff)) - bfu((u16)(tt##i.x & 0xffff)), bfu((u16)(tt##i.x & 0xffff))) * bfu((u16)(h##i & 0xffff)); \
    float vy##i = fmaf(fr##i, bfu((u16)(tt##i.y >> 16))    - bfu((u16)(tt##i.x >> 16)),    bfu((u16)(tt##i.x >> 16)))    * bfu((u16)(h##i >> 16));
#define GACC(i) \
    if (!(mask_self && d##i == s)) { rx += vx##i; ry += vy##i; }

__global__ __launch_bounds__(256) void k_edge_gather(const int* __restrict__ rs,
                                                     const uint2* __restrict__ ed,
                                                     const uint2* __restrict__ Tb2,
                                                     const u32* __restrict__ vh,
                                                     u32* __restrict__ accb,
                                                     int mask_self) {
    int tid = threadIdx.x;
    int g = tid >> 6, lane = tid & 63;
    int s = blockIdx.x * 4 + g;          // 2500 blocks x 4 waves = 10000 atoms
    if (s >= NATOMS) return;
    int e0 = rs[s];
    int e1 = (s < NATOMS - 1) ? rs[s + 1] : NEDGES;
    float rx = 0.f, ry = 0.f;
    int e = e0;
    for (; e + 8 <= e1; e += 8) {
        GEV(0) GEV(1) GEV(2) GEV(3) GEV(4) GEV(5) GEV(6) GEV(7)
        GACC(0) GACC(1) GACC(2) GACC(3) GACC(4) GACC(5) GACC(6) GACC(7)
    }
    for (; e < e1; ++e) {
        uint2 edt = ed[e];
        int dt = (int)edt.x; float ut = __uint_as_float(edt.y);
        int ixt = min((int)ut, NT - 2); float frt = ut - (float)ixt;
        uint2 ttt = Tb2[(size_t)ixt * 64 + lane];
        u32 ht = vh[dt * 64 + lane];
        float vxt = fmaf(frt, bfu((u16)(ttt.y & 0xffff)) - bfu((u16)(ttt.x & 0xffff)), bfu((u16)(ttt.x & 0xffff))) * bfu((u16)(ht & 0xffff));
        float vyt = fmaf(frt, bfu((u16)(ttt.y >> 16))    - bfu((u16)(ttt.x >> 16)),    bfu((u16)(ttt.x >> 16)))    * bfu((u16)(ht >> 16));
        if (!(mask_self && dt == s)) { rx += vxt; ry += vyt; }
    }
    accb[(size_t)s * 64 + lane] = (u32)bf16r(rx) | ((u32)bf16r(ry) << 16);
}

extern "C" void kernel_launch(void* const* d_in, const int* in_sizes, int n_in,
                              void* d_out, int out_size, void* d_ws, size_t ws_size,
                              hipStream_t stream) {
    const int* z  = (const int*)d_in[0];
    const int* ei = (const int*)d_in[1];
    const void* ew        = d_in[2];
    const void* emb       = d_in[3];
    const void* means     = d_in[4];
    const void* betas     = d_in[5];
    const void* ne_proj_w = d_in[6];
    const void* ne_proj_b = d_in[7];
    const void* ne_comb_w = d_in[8];
    const void* ne_comb_b = d_in[9];
    const void* mlp_w0    = d_in[10];
    const void* mlp_b0    = d_in[11];
    const void* mlp_w1    = d_in[12];
    const void* mlp_b1    = d_in[13];
    const void* lin1_w    = d_in[14];
    const void* lin2_w    = d_in[15];
    const void* lin2_b    = d_in[16];
    const void* lin_w     = d_in[17];
    const void* lin_b     = d_in[18];

    const int* srcp = ei;
    const int* dstp = ei + NEDGES;

    float* buf0 = (float*)d_ws;            // x0 fp32
    float* x    = buf0 + NELEM;            // persistent fp32 node state
    u32*   accb = (u32*)(x + NELEM);       // bf16x2 gather accumulator (NELEM/2 u32)
    int*   deg  = (int*)(accb + NELEM / 2);// deg[10240] + cnt[10240]
    int*   cnt  = deg + 10240;
    int*   rs   = cnt + 10240;
    uint2* ed   = (uint2*)(rs + 10240);    // CSR edge data {dst, ew bits}
    u16*   Tb2  = (u16*)(ed + NEDGES);     // NE table, paired: NT x 256 u16 (2MB)
    u16*   hb   = Tb2 + (size_t)NT * 256;  // bf16 h / x0 mirror
    u16*   ftT2 = hb + NELEM;              // 3 paired filter tables (3 x 2MB)

    const int gElem = (NELEM + 255) / 256;
    const int gEdge = (NEDGES + 255) / 256;

    // embed (zeroes deg/cnt)
    k_embed<<<gElem, 256, 0, stream>>>(z, emb, means, buf0, hb, deg);

    // counting sort by src -> CSR
    k_hist<<<gEdge, 256, 0, stream>>>(srcp, deg);
    k_scan<<<1, 1024, 0, stream>>>(deg, rs);
    k_scatter_perm<<<gEdge, 256, 0, stream>>>(srcp, dstp, ew, means, rs, cnt, ed);

    // all 4 tables (3 filter + NE), paired layout
    k_ft4<<<1024, 1024, 0, stream>>>(means, betas, mlp_w0, mlp_b0, mlp_w1, mlp_b1,
                                     ne_proj_w, ne_proj_b, ftT2, Tb2);

    // NeighborEmbedding edge pass (gather, no atomics)
    k_edge_gather<<<2500, 256, 0, stream>>>(rs, ed, (const uint2*)Tb2,
                                            (const u32*)hb, accb, 1);
    // combine + fused layer-0 lin1 (writes x and hb)
    k_mfma_comb<<<256, 256, 0, stream>>>(buf0, accb, ne_comb_w, ne_comb_b,
                                         lin1_w, x, hb, means);

    for (int L = 0; L < 3; ++L) {
        k_edge_gather<<<2500, 256, 0, stream>>>(rs, ed,
                                                (const uint2*)(ftT2 + (size_t)L * NT * 256),
                                                (const u32*)hb, accb, 0);
        // x += silu(a@l2w.T+b2)@lw.T + lb ; fused next-layer lin1 -> hb;
        // last layer writes d_out
        k_mfma_lin<<<256, 256, 0, stream>>>(accb, lin2_w, L * H * H, lin2_b, L * H,
                                            lin_w, L * H * H, lin_b, L * H,
                                            (L < 2) ? lin1_w : nullptr, (L + 1) * H * H,
                                            x, hb, means,
                                            (L == 2) ? d_out : nullptr);
    }
}

// Round 8
// 313.699 us; speedup vs baseline: 1.0755x; 1.0755x over previous
//
#include <hip/hip_runtime.h>
#include <hip/hip_bf16.h>

#define NATOMS 10000
#define NEDGES 320000
#define H 128
#define NRBF 50
#define NELEM (NATOMS * H)
#define NT 2048

typedef unsigned short u16;
typedef unsigned int u32;
typedef __attribute__((ext_vector_type(8))) short short8;
typedef __attribute__((ext_vector_type(4))) float float4v;
typedef __attribute__((ext_vector_type(4))) unsigned int uint4v;

__device__ __forceinline__ float bfu(u16 u) { return __uint_as_float(((u32)u) << 16); }
__device__ __forceinline__ u16 bf16r(float v) {   // RNE
    u32 u = __float_as_uint(v);
    return (u16)((u + 0x7FFFu + ((u >> 16) & 1u)) >> 16);
}
__device__ __forceinline__ float ldf(const void* p, int i, int bf) {
    return bf ? bfu(((const u16*)p)[i]) : ((const float*)p)[i];
}
__device__ __forceinline__ float silu_f(float v) { return v / (1.f + __expf(-v)); }
// inline dtype detect (proven logic r3-r17): means[49]==1.0 -> bf16 word24 hi = 0x3F80
__device__ __forceinline__ int bfflag(const void* means) {
    return ((((const u32*)means)[24] >> 16) == 0x3F80u) ? 1 : 0;
}

// ---- embed: x0 fp32 + bf16 mirror (proven scalar form); zeroes deg/cnt ----
__global__ __launch_bounds__(256) void k_embed(const int* __restrict__ z, const void* emb,
                                               const void* means,
                                               float* __restrict__ x0, u16* __restrict__ xh,
                                               int* __restrict__ degz) {
    int bf = bfflag(means);
    int i = blockIdx.x * 256 + threadIdx.x;
    if (i < 20480) degz[i] = 0;
    if (i < NELEM) {
        int n = i >> 7, f = i & 127;
        float v = ldf(emb, z[n] * H + f, bf);
        x0[i] = v;
        xh[i] = bf16r(v);
    }
}

// ---- bf16 LDS weight staging for MFMA: row stride 136 u16 (68 u32).
// R23 proven: 16B vector loads + 16B LDS writes (row byte stride 272 = 17*16).
__device__ __forceinline__ void stage_w16(const void* W, int woff, int wstride,
                                          u16* sW, int tid, int nthr, int bf) {
    u32* sW32 = (u32*)sW;
    if (bf) {
        const uint4v* W4 = (const uint4v*)W;     // 8 bf16 per uint4
        for (int i = tid; i < 128 * 16; i += nthr) {
            int f2 = i >> 4, k4 = i & 15;
            uint4v v = W4[((woff + f2 * wstride) >> 3) + k4];
            *(uint4v*)&sW32[f2 * 68 + k4 * 4] = v;
        }
    } else {
        const float4* Wf4 = (const float4*)W;
        for (int i = tid; i < 128 * 16; i += nthr) {
            int f2 = i >> 4, k4 = i & 15;
            int base = ((woff + f2 * wstride) >> 2) + k4 * 2;
            float4 a = Wf4[base], b = Wf4[base + 1];
            uint4v v;
            v.x = (u32)bf16r(a.x) | ((u32)bf16r(a.y) << 16);
            v.y = (u32)bf16r(a.z) | ((u32)bf16r(a.w) << 16);
            v.z = (u32)bf16r(b.x) | ((u32)bf16r(b.y) << 16);
            v.w = (u32)bf16r(b.z) | ((u32)bf16r(b.w) << 16);
            *(uint4v*)&sW32[f2 * 68 + k4 * 4] = v;
        }
    }
}

// ---- MFMA node GEMM (R23 proven):
//   x += silu(in@W2.T+b2)@Wl.T+bl ; if W1n: hb = bf16(x_new @ W1n.T) ----
__global__ __launch_bounds__(256) void k_mfma_lin(const u32* __restrict__ in,
                                                  const void* W2, int w2off,
                                                  const void* B2, int b2off,
                                                  const void* Wl, int wloff,
                                                  const void* Bl, int bloff,
                                                  const void* W1n, int w1noff,
                                                  float* x, u16* __restrict__ hb,
                                                  const void* means,
                                                  void* outp) {
    __shared__ u16 sW2[128 * 136];
    __shared__ u16 sWl[128 * 136];
    __shared__ u16 sW1[128 * 136];
    __shared__ u16 sA[4][16 * 136];
    __shared__ float sB2v[128], sBlv[128];
    int tid = threadIdx.x;
    int bf = bfflag(means);
    stage_w16(W2, w2off, H, sW2, tid, 256, bf);
    stage_w16(Wl, wloff, H, sWl, tid, 256, bf);
    if (W1n) stage_w16(W1n, w1noff, H, sW1, tid, 256, bf);
    if (tid < 128) {
        sB2v[tid] = ldf(B2, b2off + tid, bf);
        sBlv[tid] = ldf(Bl, bloff + tid, bf);
    }
    __syncthreads();
    int w = tid >> 6, lane = tid & 63;
    int quad = lane >> 4, l16 = lane & 15;
    u16* myA = sA[w];
    u32* myA32 = (u32*)myA;
    for (int tile = blockIdx.x * 4 + w; tile < NATOMS / 16; tile += gridDim.x * 4) {
        int abase = tile * 16;
        const u32* in2 = in + (size_t)abase * 64;
        #pragma unroll 4
        for (int j = 0; j < 16; ++j)
            myA32[j * 68 + lane] = in2[j * 64 + lane];
        __asm__ volatile("s_waitcnt lgkmcnt(0)" ::: "memory");
        short8 af0 = *(const short8*)&myA[l16 * 136 +   0 + quad * 8];
        short8 af1 = *(const short8*)&myA[l16 * 136 +  32 + quad * 8];
        short8 af2 = *(const short8*)&myA[l16 * 136 +  64 + quad * 8];
        short8 af3 = *(const short8*)&myA[l16 * 136 +  96 + quad * 8];
        // GEMM 1: myA <- bf16(silu(in @ W2.T + b2))
        #pragma unroll 1
        for (int nt = 0; nt < 8; ++nt) {
            const u16* wrow = &sW2[(nt * 16 + l16) * 136];
            short8 b0 = *(const short8*)&wrow[0  + quad * 8];
            short8 b1 = *(const short8*)&wrow[32 + quad * 8];
            short8 b2 = *(const short8*)&wrow[64 + quad * 8];
            short8 b3 = *(const short8*)&wrow[96 + quad * 8];
            float4v acc = {0.f, 0.f, 0.f, 0.f};
            acc = __builtin_amdgcn_mfma_f32_16x16x32_bf16(af0, b0, acc, 0, 0, 0);
            acc = __builtin_amdgcn_mfma_f32_16x16x32_bf16(af1, b1, acc, 0, 0, 0);
            acc = __builtin_amdgcn_mfma_f32_16x16x32_bf16(af2, b2, acc, 0, 0, 0);
            acc = __builtin_amdgcn_mfma_f32_16x16x32_bf16(af3, b3, acc, 0, 0, 0);
            int col = nt * 16 + l16;
            float bias = sB2v[col];
            myA[(quad * 4 + 0) * 136 + col] = bf16r(silu_f(acc[0] + bias));
            myA[(quad * 4 + 1) * 136 + col] = bf16r(silu_f(acc[1] + bias));
            myA[(quad * 4 + 2) * 136 + col] = bf16r(silu_f(acc[2] + bias));
            myA[(quad * 4 + 3) * 136 + col] = bf16r(silu_f(acc[3] + bias));
        }
        __asm__ volatile("s_waitcnt lgkmcnt(0)" ::: "memory");
        short8 t0 = *(const short8*)&myA[l16 * 136 +   0 + quad * 8];
        short8 t1 = *(const short8*)&myA[l16 * 136 +  32 + quad * 8];
        short8 t2 = *(const short8*)&myA[l16 * 136 +  64 + quad * 8];
        short8 t3 = *(const short8*)&myA[l16 * 136 +  96 + quad * 8];
        // GEMM 2: x += t @ Wl.T + bl ; stash bf16(x_new) back to myA for GEMM 3
        #pragma unroll 1
        for (int nt = 0; nt < 8; ++nt) {
            const u16* wrow = &sWl[(nt * 16 + l16) * 136];
            short8 b0 = *(const short8*)&wrow[0  + quad * 8];
            short8 b1 = *(const short8*)&wrow[32 + quad * 8];
            short8 b2 = *(const short8*)&wrow[64 + quad * 8];
            short8 b3 = *(const short8*)&wrow[96 + quad * 8];
            int col = nt * 16 + l16;
            float bias = sBlv[col];
            float4v acc;
            acc[0] = x[(size_t)(abase + quad * 4 + 0) * H + col] + bias;
            acc[1] = x[(size_t)(abase + quad * 4 + 1) * H + col] + bias;
            acc[2] = x[(size_t)(abase + quad * 4 + 2) * H + col] + bias;
            acc[3] = x[(size_t)(abase + quad * 4 + 3) * H + col] + bias;
            acc = __builtin_amdgcn_mfma_f32_16x16x32_bf16(t0, b0, acc, 0, 0, 0);
            acc = __builtin_amdgcn_mfma_f32_16x16x32_bf16(t1, b1, acc, 0, 0, 0);
            acc = __builtin_amdgcn_mfma_f32_16x16x32_bf16(t2, b2, acc, 0, 0, 0);
            acc = __builtin_amdgcn_mfma_f32_16x16x32_bf16(t3, b3, acc, 0, 0, 0);
            #pragma unroll
            for (int r = 0; r < 4; ++r) {
                size_t idx = (size_t)(abase + quad * 4 + r) * H + col;
                x[idx] = acc[r];
                myA[(quad * 4 + r) * 136 + col] = bf16r(acc[r]);
                if (outp) {
                    if (bf) ((u16*)outp)[idx] = bf16r(acc[r]);
                    else    ((float*)outp)[idx] = acc[r];
                }
            }
        }
        // GEMM 3 (fused next-layer lin1): hb = bf16(x_new @ W1n.T), no bias
        if (W1n) {
            __asm__ volatile("s_waitcnt lgkmcnt(0)" ::: "memory");
            short8 h0 = *(const short8*)&myA[l16 * 136 +   0 + quad * 8];
            short8 h1 = *(const short8*)&myA[l16 * 136 +  32 + quad * 8];
            short8 h2 = *(const short8*)&myA[l16 * 136 +  64 + quad * 8];
            short8 h3 = *(const short8*)&myA[l16 * 136 +  96 + quad * 8];
            #pragma unroll 1
            for (int nt = 0; nt < 8; ++nt) {
                const u16* wrow = &sW1[(nt * 16 + l16) * 136];
                short8 b0 = *(const short8*)&wrow[0  + quad * 8];
                short8 b1 = *(const short8*)&wrow[32 + quad * 8];
                short8 b2 = *(const short8*)&wrow[64 + quad * 8];
                short8 b3 = *(const short8*)&wrow[96 + quad * 8];
                float4v acc = {0.f, 0.f, 0.f, 0.f};
                acc = __builtin_amdgcn_mfma_f32_16x16x32_bf16(h0, b0, acc, 0, 0, 0);
                acc = __builtin_amdgcn_mfma_f32_16x16x32_bf16(h1, b1, acc, 0, 0, 0);
                acc = __builtin_amdgcn_mfma_f32_16x16x32_bf16(h2, b2, acc, 0, 0, 0);
                acc = __builtin_amdgcn_mfma_f32_16x16x32_bf16(h3, b3, acc, 0, 0, 0);
                int col = nt * 16 + l16;
                hb[(size_t)(abase + quad * 4 + 0) * H + col] = bf16r(acc[0]);
                hb[(size_t)(abase + quad * 4 + 1) * H + col] = bf16r(acc[1]);
                hb[(size_t)(abase + quad * 4 + 2) * H + col] = bf16r(acc[2]);
                hb[(size_t)(abase + quad * 4 + 3) * H + col] = bf16r(acc[3]);
            }
        }
    }
}

// ---- MFMA NE combine (R23 proven); also hb = bf16(x @ l1w0.T) ----
__global__ __launch_bounds__(256) void k_mfma_comb(const float* in0, const u32* __restrict__ in1,
                                                   const void* W, const void* B,
                                                   const void* W1,
                                                   float* x, u16* __restrict__ hb,
                                                   const void* means) {
    __shared__ u16 sWa[128 * 136];
    __shared__ u16 sWb[128 * 136];
    __shared__ u16 sW1[128 * 136];
    __shared__ u16 sA[4][16 * 136];
    __shared__ float sBv[128];
    int tid = threadIdx.x;
    int bf = bfflag(means);
    stage_w16(W, 0,   256, sWa, tid, 256, bf);
    stage_w16(W, 128, 256, sWb, tid, 256, bf);
    stage_w16(W1, 0, H, sW1, tid, 256, bf);
    if (tid < 128) sBv[tid] = ldf(B, tid, bf);
    __syncthreads();
    int w = tid >> 6, lane = tid & 63;
    int quad = lane >> 4, l16 = lane & 15;
    u16* myA = sA[w];
    u32* myA32 = (u32*)myA;
    for (int tile = blockIdx.x * 4 + w; tile < NATOMS / 16; tile += gridDim.x * 4) {
        int abase = tile * 16;
        const float2* i0 = (const float2*)in0 + (size_t)abase * 64;
        const u32* i1 = in1 + (size_t)abase * 64;
        #pragma unroll 4
        for (int j = 0; j < 16; ++j) {
            float2 v = i0[j * 64 + lane];
            myA32[j * 68 + lane] = (u32)bf16r(v.x) | ((u32)bf16r(v.y) << 16);
        }
        __asm__ volatile("s_waitcnt lgkmcnt(0)" ::: "memory");
        short8 af0 = *(const short8*)&myA[l16 * 136 +   0 + quad * 8];
        short8 af1 = *(const short8*)&myA[l16 * 136 +  32 + quad * 8];
        short8 af2 = *(const short8*)&myA[l16 * 136 +  64 + quad * 8];
        short8 af3 = *(const short8*)&myA[l16 * 136 +  96 + quad * 8];
        #pragma unroll 4
        for (int j = 0; j < 16; ++j)
            myA32[j * 68 + lane] = i1[j * 64 + lane];
        __asm__ volatile("s_waitcnt lgkmcnt(0)" ::: "memory");
        short8 ag0 = *(const short8*)&myA[l16 * 136 +   0 + quad * 8];
        short8 ag1 = *(const short8*)&myA[l16 * 136 +  32 + quad * 8];
        short8 ag2 = *(const short8*)&myA[l16 * 136 +  64 + quad * 8];
        short8 ag3 = *(const short8*)&myA[l16 * 136 +  96 + quad * 8];
        #pragma unroll 1
        for (int nt = 0; nt < 8; ++nt) {
            const u16* wra = &sWa[(nt * 16 + l16) * 136];
            const u16* wrb = &sWb[(nt * 16 + l16) * 136];
            int col = nt * 16 + l16;
            float bias = sBv[col];
            float4v acc = {bias, bias, bias, bias};
            acc = __builtin_amdgcn_mfma_f32_16x16x32_bf16(af0, *(const short8*)&wra[0  + quad * 8], acc, 0, 0, 0);
            acc = __builtin_amdgcn_mfma_f32_16x16x32_bf16(af1, *(const short8*)&wra[32 + quad * 8], acc, 0, 0, 0);
            acc = __builtin_amdgcn_mfma_f32_16x16x32_bf16(af2, *(const short8*)&wra[64 + quad * 8], acc, 0, 0, 0);
            acc = __builtin_amdgcn_mfma_f32_16x16x32_bf16(af3, *(const short8*)&wra[96 + quad * 8], acc, 0, 0, 0);
            acc = __builtin_amdgcn_mfma_f32_16x16x32_bf16(ag0, *(const short8*)&wrb[0  + quad * 8], acc, 0, 0, 0);
            acc = __builtin_amdgcn_mfma_f32_16x16x32_bf16(ag1, *(const short8*)&wrb[32 + quad * 8], acc, 0, 0, 0);
            acc = __builtin_amdgcn_mfma_f32_16x16x32_bf16(ag2, *(const short8*)&wrb[64 + quad * 8], acc, 0, 0, 0);
            acc = __builtin_amdgcn_mfma_f32_16x16x32_bf16(ag3, *(const short8*)&wrb[96 + quad * 8], acc, 0, 0, 0);
            #pragma unroll
            for (int r = 0; r < 4; ++r) {
                x[(size_t)(abase + quad * 4 + r) * H + col] = acc[r];
                myA[(quad * 4 + r) * 136 + col] = bf16r(acc[r]);
            }
        }
        // fused layer-0 lin1: hb = bf16(x @ l1w0.T)
        __asm__ volatile("s_waitcnt lgkmcnt(0)" ::: "memory");
        short8 h0 = *(const short8*)&myA[l16 * 136 +   0 + quad * 8];
        short8 h1 = *(const short8*)&myA[l16 * 136 +  32 + quad * 8];
        short8 h2 = *(const short8*)&myA[l16 * 136 +  64 + quad * 8];
        short8 h3 = *(const short8*)&myA[l16 * 136 +  96 + quad * 8];
        #pragma unroll 1
        for (int nt = 0; nt < 8; ++nt) {
            const u16* wrow = &sW1[(nt * 16 + l16) * 136];
            short8 b0 = *(const short8*)&wrow[0  + quad * 8];
            short8 b1 = *(const short8*)&wrow[32 + quad * 8];
            short8 b2 = *(const short8*)&wrow[64 + quad * 8];
            short8 b3 = *(const short8*)&wrow[96 + quad * 8];
            float4v acc = {0.f, 0.f, 0.f, 0.f};
            acc = __builtin_amdgcn_mfma_f32_16x16x32_bf16(h0, b0, acc, 0, 0, 0);
            acc = __builtin_amdgcn_mfma_f32_16x16x32_bf16(h1, b1, acc, 0, 0, 0);
            acc = __builtin_amdgcn_mfma_f32_16x16x32_bf16(h2, b2, acc, 0, 0, 0);
            acc = __builtin_amdgcn_mfma_f32_16x16x32_bf16(h3, b3, acc, 0, 0, 0);
            int col = nt * 16 + l16;
            hb[(size_t)(abase + quad * 4 + 0) * H + col] = bf16r(acc[0]);
            hb[(size_t)(abase + quad * 4 + 1) * H + col] = bf16r(acc[1]);
            hb[(size_t)(abase + quad * 4 + 2) * H + col] = bf16r(acc[2]);
            hb[(size_t)(abase + quad * 4 + 3) * H + col] = bf16r(acc[3]);
        }
    }
}

// ---- all 4 tables in one launch (R25: NT=2048, 128 blocks/table, grid 512):
//      t=0..2 filter tables, t=3 NE table ----
__global__ __launch_bounds__(1024) void k_ft4(const void* means, const void* betas,
                                              const void* W0s, const void* B0s,
                                              const void* W1s, const void* B1s,
                                              const void* Wne, const void* Bne,
                                              u16* __restrict__ ftT,
                                              u16* __restrict__ Tne) {
    __shared__ float sW0[H * 53];
    __shared__ u16 sW1b[128 * 136];
    __shared__ u16 sA16[16 * 136];
    __shared__ float sR[16][56];
    __shared__ float sM[NRBF], sBe[NRBF], sB1v[128], sC[16];
    int tid = threadIdx.x;
    int bf = bfflag(means);
    int t = blockIdx.x >> 7;                 // 0..2 = layer filter, 3 = NE table
    int bb = blockIdx.x & 127;               // 128 blocks per table (NT/16)
    int ne = (t == 3);
    const void* W0 = ne ? Wne : W0s;
    int w0off = ne ? 0 : t * H * NRBF;
    u16* T = ne ? Tne : (ftT + (size_t)t * NT * H);
    if (!ne) stage_w16(W1s, t * H * H, H, sW1b, tid, 1024, bf);
    for (int i = tid; i < H * NRBF; i += 1024) {
        int f2 = i / NRBF, k = i - f2 * NRBF;
        sW0[f2 * 53 + k] = ldf(W0, w0off + i, bf);
    }
    if (tid < NRBF) { sM[tid] = ldf(means, tid, bf); sBe[tid] = ldf(betas, tid, bf); }
    if (tid < 128) sB1v[tid] = ne ? 0.f : ldf(B1s, t * H + tid, bf);
    __syncthreads();
    int g = tid >> 7, f = tid & 127;
    float b0r = ne ? ldf(Bne, f, bf) : ldf(B0s, t * H + f, bf);
    int base = bb * 16;
    int n0 = base + 2 * g, n1 = n0 + 1;
    float wv0 = (float)n0 * (5.0f / (NT - 1));
    float wv1 = (float)n1 * (5.0f / (NT - 1));
    if (f < NRBF) {
        float tt = expf(-wv0) - sM[f];
        sR[2 * g][f] = expf(-sBe[f] * tt * tt);
    } else if (f >= 64 && f < 64 + NRBF) {
        float tt = expf(-wv1) - sM[f - 64];
        sR[2 * g + 1][f - 64] = expf(-sBe[f - 64] * tt * tt);
    }
    __syncthreads();
    float c0 = 0.5f * (cosf(wv0 * 0.62831853071795864f) + 1.f); if (!(wv0 < 5.f)) c0 = 0.f;
    float c1 = 0.5f * (cosf(wv1 * 0.62831853071795864f) + 1.f); if (!(wv1 < 5.f)) c1 = 0.f;
    if (f == 0) { sC[2 * g] = c0; sC[2 * g + 1] = c1; }
    float s0 = 0.f, s1 = 0.f;
    #pragma unroll
    for (int k = 0; k < NRBF; ++k) {
        float wk = sW0[f * 53 + k];
        s0 = fmaf(wk, sR[2 * g][k], s0);
        s1 = fmaf(wk, sR[2 * g + 1][k], s1);
    }
    if (ne) {   // NE table: T = (c*acc + b)*c — block-uniform branch, safe return
        T[(size_t)n0 * H + f] = bf16r(fmaf(c0, s0, b0r) * c0);
        T[(size_t)n1 * H + f] = bf16r(fmaf(c1, s1, b0r) * c1);
        return;
    }
    sA16[(2 * g) * 136 + f]     = bf16r(silu_f(fmaf(c0, s0, b0r)));
    sA16[(2 * g + 1) * 136 + f] = bf16r(silu_f(fmaf(c1, s1, b0r)));
    __syncthreads();
    int w = tid >> 6;
    if (w < 8) {
        int lane = tid & 63;
        int quad = lane >> 4, l16 = lane & 15;
        short8 a0 = *(const short8*)&sA16[l16 * 136 +   0 + quad * 8];
        short8 a1 = *(const short8*)&sA16[l16 * 136 +  32 + quad * 8];
        short8 a2 = *(const short8*)&sA16[l16 * 136 +  64 + quad * 8];
        short8 a3 = *(const short8*)&sA16[l16 * 136 +  96 + quad * 8];
        const u16* wrow = &sW1b[(w * 16 + l16) * 136];
        short8 b0 = *(const short8*)&wrow[0  + quad * 8];
        short8 b1 = *(const short8*)&wrow[32 + quad * 8];
        short8 b2 = *(const short8*)&wrow[64 + quad * 8];
        short8 b3 = *(const short8*)&wrow[96 + quad * 8];
        float4v acc = {0.f, 0.f, 0.f, 0.f};
        acc = __builtin_amdgcn_mfma_f32_16x16x32_bf16(a0, b0, acc, 0, 0, 0);
        acc = __builtin_amdgcn_mfma_f32_16x16x32_bf16(a1, b1, acc, 0, 0, 0);
        acc = __builtin_amdgcn_mfma_f32_16x16x32_bf16(a2, b2, acc, 0, 0, 0);
        acc = __builtin_amdgcn_mfma_f32_16x16x32_bf16(a3, b3, acc, 0, 0, 0);
        int col = w * 16 + l16;
        float bias = sB1v[col];
        #pragma unroll
        for (int r = 0; r < 4; ++r) {
            int row = quad * 4 + r;
            T[(size_t)(base + row) * H + col] = bf16r((acc[r] + bias) * sC[row]);
        }
    }
}

// ---- counting sort by src (proven) ----
__global__ __launch_bounds__(256) void k_hist(const int* __restrict__ src, int* __restrict__ deg) {
    int e = blockIdx.x * 256 + threadIdx.x;
    if (e < NEDGES) atomicAdd(&deg[src[e]], 1);
}

// ---- R20: shuffle-based exclusive scan, 3 barriers.
__global__ __launch_bounds__(1024) void k_scan(const int* __restrict__ deg, int* __restrict__ rs) {
    __shared__ int wsum[16];
    int tid = threadIdx.x;
    int lane = tid & 63, w = tid >> 6;
    int d[10];
    int tot = 0;
    int base_i = tid * 10;
    if (tid < 1000) {
        #pragma unroll
        for (int j = 0; j < 10; ++j) d[j] = deg[base_i + j];
        #pragma unroll
        for (int j = 0; j < 10; ++j) { int v = d[j]; d[j] = tot; tot += v; }
    }
    int inc = tot;
    #pragma unroll
    for (int off = 1; off < 64; off <<= 1) {
        int n = __shfl_up(inc, off, 64);
        if (lane >= off) inc += n;
    }
    if (lane == 63) wsum[w] = inc;
    __syncthreads();
    if (w == 0) {
        int v = (lane < 16) ? wsum[lane] : 0;
        int vinc = v;
        #pragma unroll
        for (int off = 1; off < 16; off <<= 1) {
            int n = __shfl_up(vinc, off, 64);
            if (lane >= off) vinc += n;
        }
        if (lane < 16) wsum[lane] = vinc - v;   // exclusive wave offsets
    }
    __syncthreads();
    if (tid < 1000) {
        int base = wsum[w] + (inc - tot);
        #pragma unroll
        for (int j = 0; j < 10; ++j) rs[base_i + j] = base + d[j];
    }
}

// ---- R21: CSR edge data — one uint2 {dst, ew_scaled_bits} per edge ----
__global__ __launch_bounds__(256) void k_scatter_perm(const int* __restrict__ src,
                                                      const int* __restrict__ dst,
                                                      const void* ew, const void* means,
                                                      const int* __restrict__ rs,
                                                      int* __restrict__ cnt,
                                                      uint2* __restrict__ ed) {
    int bf = bfflag(means);
    int e = blockIdx.x * 256 + threadIdx.x;
    if (e < NEDGES) {
        int s = src[e];
        int p = rs[s] + atomicAdd(&cnt[s], 1);
        float u = ldf(ew, e, bf) * ((float)(NT - 1) / 5.0f);   // pre-scaled
        ed[p] = make_uint2((u32)dst[e], __float_as_uint(u));
    }
}

// ---- R21: GATHER edge aggregation — one wave per atom, CSR walk, zero atomics.
#define GEV(i) \
    uint2 ed##i = ed[e + i]; \
    int d##i = (int)ed##i.x; float u##i = __uint_as_float(ed##i.y); \
    int ix##i = min((int)u##i, NT - 2); float fr##i = u##i - (float)ix##i; \
    u32 ta##i = Tb[ix##i * 64 + lane], tb##i = Tb[ix##i * 64 + 64 + lane]; \
    u32 h##i = vh[d##i * 64 + lane]; \
    float vx##i = fmaf(fr##i, bfu((u16)(tb##i & 0xffff)) - bfu((u16)(ta##i & 0xffff)), bfu((u16)(ta##i & 0xffff))) * bfu((u16)(h##i & 0xffff)); \
    float vy##i = fmaf(fr##i, bfu((u16)(tb##i >> 16))    - bfu((u16)(ta##i >> 16)),    bfu((u16)(ta##i >> 16)))    * bfu((u16)(h##i >> 16));
#define GACC(i) \
    if (!(mask_self && d##i == s)) { rx += vx##i; ry += vy##i; }

__global__ __launch_bounds__(256) void k_edge_gather(const int* __restrict__ rs,
                                                     const uint2* __restrict__ ed,
                                                     const u32* __restrict__ Tb,
                                                     const u32* __restrict__ vh,
                                                     u32* __restrict__ accb,
                                                     int mask_self) {
    int tid = threadIdx.x;
    int g = tid >> 6, lane = tid & 63;
    int s = blockIdx.x * 4 + g;          // 2500 blocks x 4 waves = 10000 atoms
    if (s >= NATOMS) return;
    int e0 = rs[s];
    int e1 = (s < NATOMS - 1) ? rs[s + 1] : NEDGES;
    float rx = 0.f, ry = 0.f;
    int e = e0;
    for (; e + 8 <= e1; e += 8) {
        GEV(0) GEV(1) GEV(2) GEV(3) GEV(4) GEV(5) GEV(6) GEV(7)
        GACC(0) GACC(1) GACC(2) GACC(3) GACC(4) GACC(5) GACC(6) GACC(7)
    }
    for (; e < e1; ++e) {
        uint2 edt = ed[e];
        int dt = (int)edt.x; float ut = __uint_as_float(edt.y);
        int ixt = min((int)ut, NT - 2); float frt = ut - (float)ixt;
        u32 tat = Tb[ixt * 64 + lane], tbt = Tb[ixt * 64 + 64 + lane];
        u32 ht = vh[dt * 64 + lane];
        float vxt = fmaf(frt, bfu((u16)(tbt & 0xffff)) - bfu((u16)(tat & 0xffff)), bfu((u16)(tat & 0xffff))) * bfu((u16)(ht & 0xffff));
        float vyt = fmaf(frt, bfu((u16)(tbt >> 16))    - bfu((u16)(tat >> 16)),    bfu((u16)(tat >> 16)))    * bfu((u16)(ht >> 16));
        if (!(mask_self && dt == s)) { rx += vxt; ry += vyt; }
    }
    accb[(size_t)s * 64 + lane] = (u32)bf16r(rx) | ((u32)bf16r(ry) << 16);
}

extern "C" void kernel_launch(void* const* d_in, const int* in_sizes, int n_in,
                              void* d_out, int out_size, void* d_ws, size_t ws_size,
                              hipStream_t stream) {
    const int* z  = (const int*)d_in[0];
    const int* ei = (const int*)d_in[1];
    const void* ew        = d_in[2];
    const void* emb       = d_in[3];
    const void* means     = d_in[4];
    const void* betas     = d_in[5];
    const void* ne_proj_w = d_in[6];
    const void* ne_proj_b = d_in[7];
    const void* ne_comb_w = d_in[8];
    const void* ne_comb_b = d_in[9];
    const void* mlp_w0    = d_in[10];
    const void* mlp_b0    = d_in[11];
    const void* mlp_w1    = d_in[12];
    const void* mlp_b1    = d_in[13];
    const void* lin1_w    = d_in[14];
    const void* lin2_w    = d_in[15];
    const void* lin2_b    = d_in[16];
    const void* lin_w     = d_in[17];
    const void* lin_b     = d_in[18];

    const int* srcp = ei;
    const int* dstp = ei + NEDGES;

    float* buf0 = (float*)d_ws;            // x0 fp32
    float* x    = buf0 + NELEM;            // persistent fp32 node state
    u32*   accb = (u32*)(x + NELEM);       // bf16x2 gather accumulator (NELEM/2 u32)
    int*   deg  = (int*)(accb + NELEM / 2);// deg[10240] + cnt[10240]
    int*   cnt  = deg + 10240;
    int*   rs   = cnt + 10240;
    uint2* ed   = (uint2*)(rs + 10240);    // CSR edge data {dst, ew bits}
    u16*   Tb   = (u16*)(ed + NEDGES);     // NE table, NT x 128 bf16 (0.5MB)
    u16*   hb   = Tb + NT * H;             // bf16 h / x0 mirror
    u16*   ftT  = hb + NELEM;              // 3 filter tables (3 x 0.5MB)

    const int gElem = (NELEM + 255) / 256;
    const int gEdge = (NEDGES + 255) / 256;

    // embed (zeroes deg/cnt)
    k_embed<<<gElem, 256, 0, stream>>>(z, emb, means, buf0, hb, deg);

    // counting sort by src -> CSR
    k_hist<<<gEdge, 256, 0, stream>>>(srcp, deg);
    k_scan<<<1, 1024, 0, stream>>>(deg, rs);
    k_scatter_perm<<<gEdge, 256, 0, stream>>>(srcp, dstp, ew, means, rs, cnt, ed);

    // all 4 tables (3 filter + NE), NT=2048: 4 x 128 blocks
    k_ft4<<<512, 1024, 0, stream>>>(means, betas, mlp_w0, mlp_b0, mlp_w1, mlp_b1,
                                    ne_proj_w, ne_proj_b, ftT, Tb);

    // NeighborEmbedding edge pass (gather, no atomics)
    k_edge_gather<<<2500, 256, 0, stream>>>(rs, ed, (const u32*)Tb,
                                            (const u32*)hb, accb, 1);
    // combine + fused layer-0 lin1 (writes x and hb)
    k_mfma_comb<<<256, 256, 0, stream>>>(buf0, accb, ne_comb_w, ne_comb_b,
                                         lin1_w, x, hb, means);

    for (int L = 0; L < 3; ++L) {
        k_edge_gather<<<2500, 256, 0, stream>>>(rs, ed,
                                                (const u32*)(ftT + (size_t)L * NT * H),
                                                (const u32*)hb, accb, 0);
        // x += silu(a@l2w.T+b2)@lw.T + lb ; fused next-layer lin1 -> hb;
        // last layer writes d_out
        k_mfma_lin<<<256, 256, 0, stream>>>(accb, lin2_w, L * H * H, lin2_b, L * H,
                                            lin_w, L * H * H, lin_b, L * H,
                                            (L < 2) ? lin1_w : nullptr, (L + 1) * H * H,
                                            x, hb, means,
                                            (L == 2) ? d_out : nullptr);
    }
}

// Round 9
// 311.919 us; speedup vs baseline: 1.0816x; 1.0057x over previous
//
#include <hip/hip_runtime.h>
#include <hip/hip_bf16.h>

#define NATOMS 10000
#define NEDGES 320000
#define H 128
#define NRBF 50
#define NELEM (NATOMS * H)
#define NT 2048

typedef unsigned short u16;
typedef unsigned int u32;
typedef __attribute__((ext_vector_type(8))) short short8;
typedef __attribute__((ext_vector_type(4))) float float4v;
typedef __attribute__((ext_vector_type(4))) unsigned int uint4v;

__device__ __forceinline__ float bfu(u16 u) { return __uint_as_float(((u32)u) << 16); }
__device__ __forceinline__ u16 bf16r(float v) {   // RNE
    u32 u = __float_as_uint(v);
    return (u16)((u + 0x7FFFu + ((u >> 16) & 1u)) >> 16);
}
__device__ __forceinline__ float ldf(const void* p, int i, int bf) {
    return bf ? bfu(((const u16*)p)[i]) : ((const float*)p)[i];
}
__device__ __forceinline__ float silu_f(float v) { return v / (1.f + __expf(-v)); }
// inline dtype detect (proven logic r3-r17): means[49]==1.0 -> bf16 word24 hi = 0x3F80
__device__ __forceinline__ int bfflag(const void* means) {
    return ((((const u32*)means)[24] >> 16) == 0x3F80u) ? 1 : 0;
}

// ---- embed: x0 fp32 + bf16 mirror, 4 elems/thread (R26 vectorized, audited);
//      zeroes deg/cnt ----
__global__ __launch_bounds__(256) void k_embed(const int* __restrict__ z, const void* emb,
                                               const void* means,
                                               float* __restrict__ x0, u16* __restrict__ xh,
                                               int* __restrict__ degz) {
    int bf = bfflag(means);
    int t = blockIdx.x * 256 + threadIdx.x;      // 0 .. NELEM/4-1 (grid 1250)
    if (t < 20480) degz[t] = 0;
    if (t < NELEM / 4) {
        int n = t >> 5, f4 = (t & 31) * 4;       // 32 threads per atom row
        if (bf) {
            uint2 raw = *(const uint2*)((const u16*)emb + (size_t)z[n] * H + f4);
            float4 v;
            v.x = bfu((u16)(raw.x & 0xffff)); v.y = bfu((u16)(raw.x >> 16));
            v.z = bfu((u16)(raw.y & 0xffff)); v.w = bfu((u16)(raw.y >> 16));
            *(float4*)&x0[(size_t)n * H + f4] = v;
            *(uint2*)&xh[(size_t)n * H + f4] = raw;   // exact bf16 roundtrip
        } else {
            float4 v = *(const float4*)((const float*)emb + (size_t)z[n] * H + f4);
            *(float4*)&x0[(size_t)n * H + f4] = v;
            uint2 p;
            p.x = (u32)bf16r(v.x) | ((u32)bf16r(v.y) << 16);
            p.y = (u32)bf16r(v.z) | ((u32)bf16r(v.w) << 16);
            *(uint2*)&xh[(size_t)n * H + f4] = p;
        }
    }
}

// ---- bf16 LDS weight staging for MFMA: row stride 136 u16 (68 u32).
// R23 proven: 16B vector loads + 16B LDS writes (row byte stride 272 = 17*16).
__device__ __forceinline__ void stage_w16(const void* W, int woff, int wstride,
                                          u16* sW, int tid, int nthr, int bf) {
    u32* sW32 = (u32*)sW;
    if (bf) {
        const uint4v* W4 = (const uint4v*)W;     // 8 bf16 per uint4
        for (int i = tid; i < 128 * 16; i += nthr) {
            int f2 = i >> 4, k4 = i & 15;
            uint4v v = W4[((woff + f2 * wstride) >> 3) + k4];
            *(uint4v*)&sW32[f2 * 68 + k4 * 4] = v;
        }
    } else {
        const float4* Wf4 = (const float4*)W;
        for (int i = tid; i < 128 * 16; i += nthr) {
            int f2 = i >> 4, k4 = i & 15;
            int base = ((woff + f2 * wstride) >> 2) + k4 * 2;
            float4 a = Wf4[base], b = Wf4[base + 1];
            uint4v v;
            v.x = (u32)bf16r(a.x) | ((u32)bf16r(a.y) << 16);
            v.y = (u32)bf16r(a.z) | ((u32)bf16r(a.w) << 16);
            v.z = (u32)bf16r(b.x) | ((u32)bf16r(b.y) << 16);
            v.w = (u32)bf16r(b.z) | ((u32)bf16r(b.w) << 16);
            *(uint4v*)&sW32[f2 * 68 + k4 * 4] = v;
        }
    }
}

// ---- MFMA node GEMM (R26: GEMM2 x-loads hoisted to overlap GEMM1):
//   x += silu(in@W2.T+b2)@Wl.T+bl ; if W1n: hb = bf16(x_new @ W1n.T) ----
__global__ __launch_bounds__(256) void k_mfma_lin(const u32* __restrict__ in,
                                                  const void* W2, int w2off,
                                                  const void* B2, int b2off,
                                                  const void* Wl, int wloff,
                                                  const void* Bl, int bloff,
                                                  const void* W1n, int w1noff,
                                                  float* x, u16* __restrict__ hb,
                                                  const void* means,
                                                  void* outp) {
    __shared__ u16 sW2[128 * 136];
    __shared__ u16 sWl[128 * 136];
    __shared__ u16 sW1[128 * 136];
    __shared__ u16 sA[4][16 * 136];
    __shared__ float sB2v[128], sBlv[128];
    int tid = threadIdx.x;
    int bf = bfflag(means);
    stage_w16(W2, w2off, H, sW2, tid, 256, bf);
    stage_w16(Wl, wloff, H, sWl, tid, 256, bf);
    if (W1n) stage_w16(W1n, w1noff, H, sW1, tid, 256, bf);
    if (tid < 128) {
        sB2v[tid] = ldf(B2, b2off + tid, bf);
        sBlv[tid] = ldf(Bl, bloff + tid, bf);
    }
    __syncthreads();
    int w = tid >> 6, lane = tid & 63;
    int quad = lane >> 4, l16 = lane & 15;
    u16* myA = sA[w];
    u32* myA32 = (u32*)myA;
    for (int tile = blockIdx.x * 4 + w; tile < NATOMS / 16; tile += gridDim.x * 4) {
        int abase = tile * 16;
        // R26: hoist GEMM2's x-reads — issue all 32 loads now so they overlap
        // the A-staging + GEMM1 below (fully unrolled -> stays in VGPRs).
        float xv[8][4];
        #pragma unroll
        for (int nt = 0; nt < 8; ++nt) {
            int col = nt * 16 + l16;
            #pragma unroll
            for (int r = 0; r < 4; ++r)
                xv[nt][r] = x[(size_t)(abase + quad * 4 + r) * H + col];
        }
        const u32* in2 = in + (size_t)abase * 64;
        #pragma unroll 4
        for (int j = 0; j < 16; ++j)
            myA32[j * 68 + lane] = in2[j * 64 + lane];
        __asm__ volatile("s_waitcnt lgkmcnt(0)" ::: "memory");
        short8 af0 = *(const short8*)&myA[l16 * 136 +   0 + quad * 8];
        short8 af1 = *(const short8*)&myA[l16 * 136 +  32 + quad * 8];
        short8 af2 = *(const short8*)&myA[l16 * 136 +  64 + quad * 8];
        short8 af3 = *(const short8*)&myA[l16 * 136 +  96 + quad * 8];
        // GEMM 1: myA <- bf16(silu(in @ W2.T + b2))
        #pragma unroll 1
        for (int nt = 0; nt < 8; ++nt) {
            const u16* wrow = &sW2[(nt * 16 + l16) * 136];
            short8 b0 = *(const short8*)&wrow[0  + quad * 8];
            short8 b1 = *(const short8*)&wrow[32 + quad * 8];
            short8 b2 = *(const short8*)&wrow[64 + quad * 8];
            short8 b3 = *(const short8*)&wrow[96 + quad * 8];
            float4v acc = {0.f, 0.f, 0.f, 0.f};
            acc = __builtin_amdgcn_mfma_f32_16x16x32_bf16(af0, b0, acc, 0, 0, 0);
            acc = __builtin_amdgcn_mfma_f32_16x16x32_bf16(af1, b1, acc, 0, 0, 0);
            acc = __builtin_amdgcn_mfma_f32_16x16x32_bf16(af2, b2, acc, 0, 0, 0);
            acc = __builtin_amdgcn_mfma_f32_16x16x32_bf16(af3, b3, acc, 0, 0, 0);
            int col = nt * 16 + l16;
            float bias = sB2v[col];
            myA[(quad * 4 + 0) * 136 + col] = bf16r(silu_f(acc[0] + bias));
            myA[(quad * 4 + 1) * 136 + col] = bf16r(silu_f(acc[1] + bias));
            myA[(quad * 4 + 2) * 136 + col] = bf16r(silu_f(acc[2] + bias));
            myA[(quad * 4 + 3) * 136 + col] = bf16r(silu_f(acc[3] + bias));
        }
        __asm__ volatile("s_waitcnt lgkmcnt(0)" ::: "memory");
        short8 t0 = *(const short8*)&myA[l16 * 136 +   0 + quad * 8];
        short8 t1 = *(const short8*)&myA[l16 * 136 +  32 + quad * 8];
        short8 t2 = *(const short8*)&myA[l16 * 136 +  64 + quad * 8];
        short8 t3 = *(const short8*)&myA[l16 * 136 +  96 + quad * 8];
        // GEMM 2: x += t @ Wl.T + bl ; stash bf16(x_new) back to myA for GEMM 3
        #pragma unroll 1
        for (int nt = 0; nt < 8; ++nt) {
            const u16* wrow = &sWl[(nt * 16 + l16) * 136];
            short8 b0 = *(const short8*)&wrow[0  + quad * 8];
            short8 b1 = *(const short8*)&wrow[32 + quad * 8];
            short8 b2 = *(const short8*)&wrow[64 + quad * 8];
            short8 b3 = *(const short8*)&wrow[96 + quad * 8];
            int col = nt * 16 + l16;
            float bias = sBlv[col];
            float4v acc;
            acc[0] = xv[nt][0] + bias;
            acc[1] = xv[nt][1] + bias;
            acc[2] = xv[nt][2] + bias;
            acc[3] = xv[nt][3] + bias;
            acc = __builtin_amdgcn_mfma_f32_16x16x32_bf16(t0, b0, acc, 0, 0, 0);
            acc = __builtin_amdgcn_mfma_f32_16x16x32_bf16(t1, b1, acc, 0, 0, 0);
            acc = __builtin_amdgcn_mfma_f32_16x16x32_bf16(t2, b2, acc, 0, 0, 0);
            acc = __builtin_amdgcn_mfma_f32_16x16x32_bf16(t3, b3, acc, 0, 0, 0);
            #pragma unroll
            for (int r = 0; r < 4; ++r) {
                size_t idx = (size_t)(abase + quad * 4 + r) * H + col;
                x[idx] = acc[r];
                myA[(quad * 4 + r) * 136 + col] = bf16r(acc[r]);
                if (outp) {
                    if (bf) ((u16*)outp)[idx] = bf16r(acc[r]);
                    else    ((float*)outp)[idx] = acc[r];
                }
            }
        }
        // GEMM 3 (fused next-layer lin1): hb = bf16(x_new @ W1n.T), no bias
        if (W1n) {
            __asm__ volatile("s_waitcnt lgkmcnt(0)" ::: "memory");
            short8 h0 = *(const short8*)&myA[l16 * 136 +   0 + quad * 8];
            short8 h1 = *(const short8*)&myA[l16 * 136 +  32 + quad * 8];
            short8 h2 = *(const short8*)&myA[l16 * 136 +  64 + quad * 8];
            short8 h3 = *(const short8*)&myA[l16 * 136 +  96 + quad * 8];
            #pragma unroll 1
            for (int nt = 0; nt < 8; ++nt) {
                const u16* wrow = &sW1[(nt * 16 + l16) * 136];
                short8 b0 = *(const short8*)&wrow[0  + quad * 8];
                short8 b1 = *(const short8*)&wrow[32 + quad * 8];
                short8 b2 = *(const short8*)&wrow[64 + quad * 8];
                short8 b3 = *(const short8*)&wrow[96 + quad * 8];
                float4v acc = {0.f, 0.f, 0.f, 0.f};
                acc = __builtin_amdgcn_mfma_f32_16x16x32_bf16(h0, b0, acc, 0, 0, 0);
                acc = __builtin_amdgcn_mfma_f32_16x16x32_bf16(h1, b1, acc, 0, 0, 0);
                acc = __builtin_amdgcn_mfma_f32_16x16x32_bf16(h2, b2, acc, 0, 0, 0);
                acc = __builtin_amdgcn_mfma_f32_16x16x32_bf16(h3, b3, acc, 0, 0, 0);
                int col = nt * 16 + l16;
                hb[(size_t)(abase + quad * 4 + 0) * H + col] = bf16r(acc[0]);
                hb[(size_t)(abase + quad * 4 + 1) * H + col] = bf16r(acc[1]);
                hb[(size_t)(abase + quad * 4 + 2) * H + col] = bf16r(acc[2]);
                hb[(size_t)(abase + quad * 4 + 3) * H + col] = bf16r(acc[3]);
            }
        }
    }
}

// ---- MFMA NE combine (R23 proven); also hb = bf16(x @ l1w0.T) ----
__global__ __launch_bounds__(256) void k_mfma_comb(const float* in0, const u32* __restrict__ in1,
                                                   const void* W, const void* B,
                                                   const void* W1,
                                                   float* x, u16* __restrict__ hb,
                                                   const void* means) {
    __shared__ u16 sWa[128 * 136];
    __shared__ u16 sWb[128 * 136];
    __shared__ u16 sW1[128 * 136];
    __shared__ u16 sA[4][16 * 136];
    __shared__ float sBv[128];
    int tid = threadIdx.x;
    int bf = bfflag(means);
    stage_w16(W, 0,   256, sWa, tid, 256, bf);
    stage_w16(W, 128, 256, sWb, tid, 256, bf);
    stage_w16(W1, 0, H, sW1, tid, 256, bf);
    if (tid < 128) sBv[tid] = ldf(B, tid, bf);
    __syncthreads();
    int w = tid >> 6, lane = tid & 63;
    int quad = lane >> 4, l16 = lane & 15;
    u16* myA = sA[w];
    u32* myA32 = (u32*)myA;
    for (int tile = blockIdx.x * 4 + w; tile < NATOMS / 16; tile += gridDim.x * 4) {
        int abase = tile * 16;
        const float2* i0 = (const float2*)in0 + (size_t)abase * 64;
        const u32* i1 = in1 + (size_t)abase * 64;
        #pragma unroll 4
        for (int j = 0; j < 16; ++j) {
            float2 v = i0[j * 64 + lane];
            myA32[j * 68 + lane] = (u32)bf16r(v.x) | ((u32)bf16r(v.y) << 16);
        }
        __asm__ volatile("s_waitcnt lgkmcnt(0)" ::: "memory");
        short8 af0 = *(const short8*)&myA[l16 * 136 +   0 + quad * 8];
        short8 af1 = *(const short8*)&myA[l16 * 136 +  32 + quad * 8];
        short8 af2 = *(const short8*)&myA[l16 * 136 +  64 + quad * 8];
        short8 af3 = *(const short8*)&myA[l16 * 136 +  96 + quad * 8];
        #pragma unroll 4
        for (int j = 0; j < 16; ++j)
            myA32[j * 68 + lane] = i1[j * 64 + lane];
        __asm__ volatile("s_waitcnt lgkmcnt(0)" ::: "memory");
        short8 ag0 = *(const short8*)&myA[l16 * 136 +   0 + quad * 8];
        short8 ag1 = *(const short8*)&myA[l16 * 136 +  32 + quad * 8];
        short8 ag2 = *(const short8*)&myA[l16 * 136 +  64 + quad * 8];
        short8 ag3 = *(const short8*)&myA[l16 * 136 +  96 + quad * 8];
        #pragma unroll 1
        for (int nt = 0; nt < 8; ++nt) {
            const u16* wra = &sWa[(nt * 16 + l16) * 136];
            const u16* wrb = &sWb[(nt * 16 + l16) * 136];
            int col = nt * 16 + l16;
            float bias = sBv[col];
            float4v acc = {bias, bias, bias, bias};
            acc = __builtin_amdgcn_mfma_f32_16x16x32_bf16(af0, *(const short8*)&wra[0  + quad * 8], acc, 0, 0, 0);
            acc = __builtin_amdgcn_mfma_f32_16x16x32_bf16(af1, *(const short8*)&wra[32 + quad * 8], acc, 0, 0, 0);
            acc = __builtin_amdgcn_mfma_f32_16x16x32_bf16(af2, *(const short8*)&wra[64 + quad * 8], acc, 0, 0, 0);
            acc = __builtin_amdgcn_mfma_f32_16x16x32_bf16(af3, *(const short8*)&wra[96 + quad * 8], acc, 0, 0, 0);
            acc = __builtin_amdgcn_mfma_f32_16x16x32_bf16(ag0, *(const short8*)&wrb[0  + quad * 8], acc, 0, 0, 0);
            acc = __builtin_amdgcn_mfma_f32_16x16x32_bf16(ag1, *(const short8*)&wrb[32 + quad * 8], acc, 0, 0, 0);
            acc = __builtin_amdgcn_mfma_f32_16x16x32_bf16(ag2, *(const short8*)&wrb[64 + quad * 8], acc, 0, 0, 0);
            acc = __builtin_amdgcn_mfma_f32_16x16x32_bf16(ag3, *(const short8*)&wrb[96 + quad * 8], acc, 0, 0, 0);
            #pragma unroll
            for (int r = 0; r < 4; ++r) {
                x[(size_t)(abase + quad * 4 + r) * H + col] = acc[r];
                myA[(quad * 4 + r) * 136 + col] = bf16r(acc[r]);
            }
        }
        // fused layer-0 lin1: hb = bf16(x @ l1w0.T)
        __asm__ volatile("s_waitcnt lgkmcnt(0)" ::: "memory");
        short8 h0 = *(const short8*)&myA[l16 * 136 +   0 + quad * 8];
        short8 h1 = *(const short8*)&myA[l16 * 136 +  32 + quad * 8];
        short8 h2 = *(const short8*)&myA[l16 * 136 +  64 + quad * 8];
        short8 h3 = *(const short8*)&myA[l16 * 136 +  96 + quad * 8];
        #pragma unroll 1
        for (int nt = 0; nt < 8; ++nt) {
            const u16* wrow = &sW1[(nt * 16 + l16) * 136];
            short8 b0 = *(const short8*)&wrow[0  + quad * 8];
            short8 b1 = *(const short8*)&wrow[32 + quad * 8];
            short8 b2 = *(const short8*)&wrow[64 + quad * 8];
            short8 b3 = *(const short8*)&wrow[96 + quad * 8];
            float4v acc = {0.f, 0.f, 0.f, 0.f};
            acc = __builtin_amdgcn_mfma_f32_16x16x32_bf16(h0, b0, acc, 0, 0, 0);
            acc = __builtin_amdgcn_mfma_f32_16x16x32_bf16(h1, b1, acc, 0, 0, 0);
            acc = __builtin_amdgcn_mfma_f32_16x16x32_bf16(h2, b2, acc, 0, 0, 0);
            acc = __builtin_amdgcn_mfma_f32_16x16x32_bf16(h3, b3, acc, 0, 0, 0);
            int col = nt * 16 + l16;
            hb[(size_t)(abase + quad * 4 + 0) * H + col] = bf16r(acc[0]);
            hb[(size_t)(abase + quad * 4 + 1) * H + col] = bf16r(acc[1]);
            hb[(size_t)(abase + quad * 4 + 2) * H + col] = bf16r(acc[2]);
            hb[(size_t)(abase + quad * 4 + 3) * H + col] = bf16r(acc[3]);
        }
    }
}

// ---- all 4 tables in one launch (R25: NT=2048, 128 blocks/table, grid 512):
//      t=0..2 filter tables, t=3 NE table ----
__global__ __launch_bounds__(1024) void k_ft4(const void* means, const void* betas,
                                              const void* W0s, const void* B0s,
                                              const void* W1s, const void* B1s,
                                              const void* Wne, const void* Bne,
                                              u16* __restrict__ ftT,
                                              u16* __restrict__ Tne) {
    __shared__ float sW0[H * 53];
    __shared__ u16 sW1b[128 * 136];
    __shared__ u16 sA16[16 * 136];
    __shared__ float sR[16][56];
    __shared__ float sM[NRBF], sBe[NRBF], sB1v[128], sC[16];
    int tid = threadIdx.x;
    int bf = bfflag(means);
    int t = blockIdx.x >> 7;                 // 0..2 = layer filter, 3 = NE table
    int bb = blockIdx.x & 127;               // 128 blocks per table (NT/16)
    int ne = (t == 3);
    const void* W0 = ne ? Wne : W0s;
    int w0off = ne ? 0 : t * H * NRBF;
    u16* T = ne ? Tne : (ftT + (size_t)t * NT * H);
    if (!ne) stage_w16(W1s, t * H * H, H, sW1b, tid, 1024, bf);
    for (int i = tid; i < H * NRBF; i += 1024) {
        int f2 = i / NRBF, k = i - f2 * NRBF;
        sW0[f2 * 53 + k] = ldf(W0, w0off + i, bf);
    }
    if (tid < NRBF) { sM[tid] = ldf(means, tid, bf); sBe[tid] = ldf(betas, tid, bf); }
    if (tid < 128) sB1v[tid] = ne ? 0.f : ldf(B1s, t * H + tid, bf);
    __syncthreads();
    int g = tid >> 7, f = tid & 127;
    float b0r = ne ? ldf(Bne, f, bf) : ldf(B0s, t * H + f, bf);
    int base = bb * 16;
    int n0 = base + 2 * g, n1 = n0 + 1;
    float wv0 = (float)n0 * (5.0f / (NT - 1));
    float wv1 = (float)n1 * (5.0f / (NT - 1));
    if (f < NRBF) {
        float tt = expf(-wv0) - sM[f];
        sR[2 * g][f] = expf(-sBe[f] * tt * tt);
    } else if (f >= 64 && f < 64 + NRBF) {
        float tt = expf(-wv1) - sM[f - 64];
        sR[2 * g + 1][f - 64] = expf(-sBe[f - 64] * tt * tt);
    }
    __syncthreads();
    float c0 = 0.5f * (cosf(wv0 * 0.62831853071795864f) + 1.f); if (!(wv0 < 5.f)) c0 = 0.f;
    float c1 = 0.5f * (cosf(wv1 * 0.62831853071795864f) + 1.f); if (!(wv1 < 5.f)) c1 = 0.f;
    if (f == 0) { sC[2 * g] = c0; sC[2 * g + 1] = c1; }
    float s0 = 0.f, s1 = 0.f;
    #pragma unroll
    for (int k = 0; k < NRBF; ++k) {
        float wk = sW0[f * 53 + k];
        s0 = fmaf(wk, sR[2 * g][k], s0);
        s1 = fmaf(wk, sR[2 * g + 1][k], s1);
    }
    if (ne) {   // NE table: T = (c*acc + b)*c — block-uniform branch, safe return
        T[(size_t)n0 * H + f] = bf16r(fmaf(c0, s0, b0r) * c0);
        T[(size_t)n1 * H + f] = bf16r(fmaf(c1, s1, b0r) * c1);
        return;
    }
    sA16[(2 * g) * 136 + f]     = bf16r(silu_f(fmaf(c0, s0, b0r)));
    sA16[(2 * g + 1) * 136 + f] = bf16r(silu_f(fmaf(c1, s1, b0r)));
    __syncthreads();
    int w = tid >> 6;
    if (w < 8) {
        int lane = tid & 63;
        int quad = lane >> 4, l16 = lane & 15;
        short8 a0 = *(const short8*)&sA16[l16 * 136 +   0 + quad * 8];
        short8 a1 = *(const short8*)&sA16[l16 * 136 +  32 + quad * 8];
        short8 a2 = *(const short8*)&sA16[l16 * 136 +  64 + quad * 8];
        short8 a3 = *(const short8*)&sA16[l16 * 136 +  96 + quad * 8];
        const u16* wrow = &sW1b[(w * 16 + l16) * 136];
        short8 b0 = *(const short8*)&wrow[0  + quad * 8];
        short8 b1 = *(const short8*)&wrow[32 + quad * 8];
        short8 b2 = *(const short8*)&wrow[64 + quad * 8];
        short8 b3 = *(const short8*)&wrow[96 + quad * 8];
        float4v acc = {0.f, 0.f, 0.f, 0.f};
        acc = __builtin_amdgcn_mfma_f32_16x16x32_bf16(a0, b0, acc, 0, 0, 0);
        acc = __builtin_amdgcn_mfma_f32_16x16x32_bf16(a1, b1, acc, 0, 0, 0);
        acc = __builtin_amdgcn_mfma_f32_16x16x32_bf16(a2, b2, acc, 0, 0, 0);
        acc = __builtin_amdgcn_mfma_f32_16x16x32_bf16(a3, b3, acc, 0, 0, 0);
        int col = w * 16 + l16;
        float bias = sB1v[col];
        #pragma unroll
        for (int r = 0; r < 4; ++r) {
            int row = quad * 4 + r;
            T[(size_t)(base + row) * H + col] = bf16r((acc[r] + bias) * sC[row]);
        }
    }
}

// ---- counting sort by src (proven) ----
__global__ __launch_bounds__(256) void k_hist(const int* __restrict__ src, int* __restrict__ deg) {
    int e = blockIdx.x * 256 + threadIdx.x;
    if (e < NEDGES) atomicAdd(&deg[src[e]], 1);
}

// ---- R20: shuffle-based exclusive scan, 3 barriers.
__global__ __launch_bounds__(1024) void k_scan(const int* __restrict__ deg, int* __restrict__ rs) {
    __shared__ int wsum[16];
    int tid = threadIdx.x;
    int lane = tid & 63, w = tid >> 6;
    int d[10];
    int tot = 0;
    int base_i = tid * 10;
    if (tid < 1000) {
        #pragma unroll
        for (int j = 0; j < 10; ++j) d[j] = deg[base_i + j];
        #pragma unroll
        for (int j = 0; j < 10; ++j) { int v = d[j]; d[j] = tot; tot += v; }
    }
    int inc = tot;
    #pragma unroll
    for (int off = 1; off < 64; off <<= 1) {
        int n = __shfl_up(inc, off, 64);
        if (lane >= off) inc += n;
    }
    if (lane == 63) wsum[w] = inc;
    __syncthreads();
    if (w == 0) {
        int v = (lane < 16) ? wsum[lane] : 0;
        int vinc = v;
        #pragma unroll
        for (int off = 1; off < 16; off <<= 1) {
            int n = __shfl_up(vinc, off, 64);
            if (lane >= off) vinc += n;
        }
        if (lane < 16) wsum[lane] = vinc - v;   // exclusive wave offsets
    }
    __syncthreads();
    if (tid < 1000) {
        int base = wsum[w] + (inc - tot);
        #pragma unroll
        for (int j = 0; j < 10; ++j) rs[base_i + j] = base + d[j];
    }
}

// ---- R21: CSR edge data — one uint2 {dst, ew_scaled_bits} per edge ----
__global__ __launch_bounds__(256) void k_scatter_perm(const int* __restrict__ src,
                                                      const int* __restrict__ dst,
                                                      const void* ew, const void* means,
                                                      const int* __restrict__ rs,
                                                      int* __restrict__ cnt,
                                                      uint2* __restrict__ ed) {
    int bf = bfflag(means);
    int e = blockIdx.x * 256 + threadIdx.x;
    if (e < NEDGES) {
        int s = src[e];
        int p = rs[s] + atomicAdd(&cnt[s], 1);
        float u = ldf(ew, e, bf) * ((float)(NT - 1) / 5.0f);   // pre-scaled
        ed[p] = make_uint2((u32)dst[e], __float_as_uint(u));
    }
}

// ---- R21: GATHER edge aggregation — one wave per atom, CSR walk, zero atomics.
#define GEV(i) \
    uint2 ed##i = ed[e + i]; \
    int d##i = (int)ed##i.x; float u##i = __uint_as_float(ed##i.y); \
    int ix##i = min((int)u##i, NT - 2); float fr##i = u##i - (float)ix##i; \
    u32 ta##i = Tb[ix##i * 64 + lane], tb##i = Tb[ix##i * 64 + 64 + lane]; \
    u32 h##i = vh[d##i * 64 + lane]; \
    float vx##i = fmaf(fr##i, bfu((u16)(tb##i & 0xffff)) - bfu((u16)(ta##i & 0xffff)), bfu((u16)(ta##i & 0xffff))) * bfu((u16)(h##i & 0xffff)); \
    float vy##i = fmaf(fr##i, bfu((u16)(tb##i >> 16))    - bfu((u16)(ta##i >> 16)),    bfu((u16)(ta##i >> 16)))    * bfu((u16)(h##i >> 16));
#define GACC(i) \
    if (!(mask_self && d##i == s)) { rx += vx##i; ry += vy##i; }

__global__ __launch_bounds__(256) void k_edge_gather(const int* __restrict__ rs,
                                                     const uint2* __restrict__ ed,
                                                     const u32* __restrict__ Tb,
                                                     const u32* __restrict__ vh,
                                                     u32* __restrict__ accb,
                                                     int mask_self) {
    int tid = threadIdx.x;
    int g = tid >> 6, lane = tid & 63;
    int s = blockIdx.x * 4 + g;          // 2500 blocks x 4 waves = 10000 atoms
    if (s >= NATOMS) return;
    int e0 = rs[s];
    int e1 = (s < NATOMS - 1) ? rs[s + 1] : NEDGES;
    float rx = 0.f, ry = 0.f;
    int e = e0;
    for (; e + 8 <= e1; e += 8) {
        GEV(0) GEV(1) GEV(2) GEV(3) GEV(4) GEV(5) GEV(6) GEV(7)
        GACC(0) GACC(1) GACC(2) GACC(3) GACC(4) GACC(5) GACC(6) GACC(7)
    }
    for (; e < e1; ++e) {
        uint2 edt = ed[e];
        int dt = (int)edt.x; float ut = __uint_as_float(edt.y);
        int ixt = min((int)ut, NT - 2); float frt = ut - (float)ixt;
        u32 tat = Tb[ixt * 64 + lane], tbt = Tb[ixt * 64 + 64 + lane];
        u32 ht = vh[dt * 64 + lane];
        float vxt = fmaf(frt, bfu((u16)(tbt & 0xffff)) - bfu((u16)(tat & 0xffff)), bfu((u16)(tat & 0xffff))) * bfu((u16)(ht & 0xffff));
        float vyt = fmaf(frt, bfu((u16)(tbt >> 16))    - bfu((u16)(tat >> 16)),    bfu((u16)(tat >> 16)))    * bfu((u16)(ht >> 16));
        if (!(mask_self && dt == s)) { rx += vxt; ry += vyt; }
    }
    accb[(size_t)s * 64 + lane] = (u32)bf16r(rx) | ((u32)bf16r(ry) << 16);
}

extern "C" void kernel_launch(void* const* d_in, const int* in_sizes, int n_in,
                              void* d_out, int out_size, void* d_ws, size_t ws_size,
                              hipStream_t stream) {
    const int* z  = (const int*)d_in[0];
    const int* ei = (const int*)d_in[1];
    const void* ew        = d_in[2];
    const void* emb       = d_in[3];
    const void* means     = d_in[4];
    const void* betas     = d_in[5];
    const void* ne_proj_w = d_in[6];
    const void* ne_proj_b = d_in[7];
    const void* ne_comb_w = d_in[8];
    const void* ne_comb_b = d_in[9];
    const void* mlp_w0    = d_in[10];
    const void* mlp_b0    = d_in[11];
    const void* mlp_w1    = d_in[12];
    const void* mlp_b1    = d_in[13];
    const void* lin1_w    = d_in[14];
    const void* lin2_w    = d_in[15];
    const void* lin2_b    = d_in[16];
    const void* lin_w     = d_in[17];
    const void* lin_b     = d_in[18];

    const int* srcp = ei;
    const int* dstp = ei + NEDGES;

    float* buf0 = (float*)d_ws;            // x0 fp32
    float* x    = buf0 + NELEM;            // persistent fp32 node state
    u32*   accb = (u32*)(x + NELEM);       // bf16x2 gather accumulator (NELEM/2 u32)
    int*   deg  = (int*)(accb + NELEM / 2);// deg[10240] + cnt[10240]
    int*   cnt  = deg + 10240;
    int*   rs   = cnt + 10240;
    uint2* ed   = (uint2*)(rs + 10240);    // CSR edge data {dst, ew bits}
    u16*   Tb   = (u16*)(ed + NEDGES);     // NE table, NT x 128 bf16 (0.5MB)
    u16*   hb   = Tb + NT * H;             // bf16 h / x0 mirror
    u16*   ftT  = hb + NELEM;              // 3 filter tables (3 x 0.5MB)

    const int gEdge = (NEDGES + 255) / 256;

    // embed, 4 elems/thread (zeroes deg/cnt)
    k_embed<<<NELEM / 4 / 256, 256, 0, stream>>>(z, emb, means, buf0, hb, deg);

    // counting sort by src -> CSR
    k_hist<<<gEdge, 256, 0, stream>>>(srcp, deg);
    k_scan<<<1, 1024, 0, stream>>>(deg, rs);
    k_scatter_perm<<<gEdge, 256, 0, stream>>>(srcp, dstp, ew, means, rs, cnt, ed);

    // all 4 tables (3 filter + NE), NT=2048: 4 x 128 blocks
    k_ft4<<<512, 1024, 0, stream>>>(means, betas, mlp_w0, mlp_b0, mlp_w1, mlp_b1,
                                    ne_proj_w, ne_proj_b, ftT, Tb);

    // NeighborEmbedding edge pass (gather, no atomics)
    k_edge_gather<<<2500, 256, 0, stream>>>(rs, ed, (const u32*)Tb,
                                            (const u32*)hb, accb, 1);
    // combine + fused layer-0 lin1 (writes x and hb)
    k_mfma_comb<<<256, 256, 0, stream>>>(buf0, accb, ne_comb_w, ne_comb_b,
                                         lin1_w, x, hb, means);

    for (int L = 0; L < 3; ++L) {
        k_edge_gather<<<2500, 256, 0, stream>>>(rs, ed,
                                                (const u32*)(ftT + (size_t)L * NT * H),
                                                (const u32*)hb, accb, 0);
        // x += silu(a@l2w.T+b2)@lw.T + lb ; fused next-layer lin1 -> hb;
        // last layer writes d_out
        k_mfma_lin<<<256, 256, 0, stream>>>(accb, lin2_w, L * H * H, lin2_b, L * H,
                                            lin_w, L * H * H, lin_b, L * H,
                                            (L < 2) ? lin1_w : nullptr, (L + 1) * H * H,
                                            x, hb, means,
                                            (L == 2) ? d_out : nullptr);
    }
}

// Round 10
// 307.526 us; speedup vs baseline: 1.0971x; 1.0143x over previous
//
#include <hip/hip_runtime.h>
#include <hip/hip_bf16.h>

#define NATOMS 10000
#define NEDGES 320000
#define H 128
#define NRBF 50
#define NELEM (NATOMS * H)
#define NT 2048

typedef unsigned short u16;
typedef unsigned int u32;
typedef __attribute__((ext_vector_type(8))) short short8;
typedef __attribute__((ext_vector_type(4))) float float4v;
typedef __attribute__((ext_vector_type(4))) unsigned int uint4v;

__device__ __forceinline__ float bfu(u16 u) { return __uint_as_float(((u32)u) << 16); }
__device__ __forceinline__ u16 bf16r(float v) {   // RNE
    u32 u = __float_as_uint(v);
    return (u16)((u + 0x7FFFu + ((u >> 16) & 1u)) >> 16);
}
__device__ __forceinline__ float ldf(const void* p, int i, int bf) {
    return bf ? bfu(((const u16*)p)[i]) : ((const float*)p)[i];
}
__device__ __forceinline__ float silu_f(float v) { return v / (1.f + __expf(-v)); }
// inline dtype detect (proven logic r3-r17): means[49]==1.0 -> bf16 word24 hi = 0x3F80
__device__ __forceinline__ int bfflag(const void* means) {
    return ((((const u32*)means)[24] >> 16) == 0x3F80u) ? 1 : 0;
}

// ---- counting sort: histogram by src (proven) ----
__global__ __launch_bounds__(256) void k_hist(const int* __restrict__ src, int* __restrict__ deg) {
    int e = blockIdx.x * 256 + threadIdx.x;
    if (e < NEDGES) atomicAdd(&deg[src[e]], 1);
}

// ---- R27 merged: blocks 0-312 = embed (R26 vectorized), block 313 = R20 scan.
// embed and scan are independent; scan needs hist done (previous kernel). ----
__global__ __launch_bounds__(1024) void k_embed_scan(const int* __restrict__ z, const void* emb,
                                                     const void* means,
                                                     float* __restrict__ x0, u16* __restrict__ xh,
                                                     const int* __restrict__ deg,
                                                     int* __restrict__ rs) {
    int tid = threadIdx.x;
    if (blockIdx.x == 313) {   // shuffle-based exclusive scan, 3 barriers
        __shared__ int wsum[16];
        int lane = tid & 63, w = tid >> 6;
        int d[10];
        int tot = 0;
        int base_i = tid * 10;
        if (tid < 1000) {
            #pragma unroll
            for (int j = 0; j < 10; ++j) d[j] = deg[base_i + j];
            #pragma unroll
            for (int j = 0; j < 10; ++j) { int v = d[j]; d[j] = tot; tot += v; }
        }
        int inc = tot;
        #pragma unroll
        for (int off = 1; off < 64; off <<= 1) {
            int n = __shfl_up(inc, off, 64);
            if (lane >= off) inc += n;
        }
        if (lane == 63) wsum[w] = inc;
        __syncthreads();
        if (w == 0) {
            int v = (lane < 16) ? wsum[lane] : 0;
            int vinc = v;
            #pragma unroll
            for (int off = 1; off < 16; off <<= 1) {
                int n = __shfl_up(vinc, off, 64);
                if (lane >= off) vinc += n;
            }
            if (lane < 16) wsum[lane] = vinc - v;   // exclusive wave offsets
        }
        __syncthreads();
        if (tid < 1000) {
            int base = wsum[w] + (inc - tot);
            #pragma unroll
            for (int j = 0; j < 10; ++j) rs[base_i + j] = base + d[j];
        }
        return;
    }
    // embed: x0 fp32 + bf16 mirror, 4 elems/thread
    int bf = bfflag(means);
    int t = blockIdx.x * 1024 + tid;             // 0 .. NELEM/4-1
    if (t < NELEM / 4) {
        int n = t >> 5, f4 = (t & 31) * 4;       // 32 threads per atom row
        if (bf) {
            uint2 raw = *(const uint2*)((const u16*)emb + (size_t)z[n] * H + f4);
            float4 v;
            v.x = bfu((u16)(raw.x & 0xffff)); v.y = bfu((u16)(raw.x >> 16));
            v.z = bfu((u16)(raw.y & 0xffff)); v.w = bfu((u16)(raw.y >> 16));
            *(float4*)&x0[(size_t)n * H + f4] = v;
            *(uint2*)&xh[(size_t)n * H + f4] = raw;   // exact bf16 roundtrip
        } else {
            float4 v = *(const float4*)((const float*)emb + (size_t)z[n] * H + f4);
            *(float4*)&x0[(size_t)n * H + f4] = v;
            uint2 p;
            p.x = (u32)bf16r(v.x) | ((u32)bf16r(v.y) << 16);
            p.y = (u32)bf16r(v.z) | ((u32)bf16r(v.w) << 16);
            *(uint2*)&xh[(size_t)n * H + f4] = p;
        }
    }
}

// ---- bf16 LDS weight staging for MFMA: row stride 136 u16 (68 u32).
// R23 proven: 16B vector loads + 16B LDS writes (row byte stride 272 = 17*16).
__device__ __forceinline__ void stage_w16(const void* W, int woff, int wstride,
                                          u16* sW, int tid, int nthr, int bf) {
    u32* sW32 = (u32*)sW;
    if (bf) {
        const uint4v* W4 = (const uint4v*)W;     // 8 bf16 per uint4
        for (int i = tid; i < 128 * 16; i += nthr) {
            int f2 = i >> 4, k4 = i & 15;
            uint4v v = W4[((woff + f2 * wstride) >> 3) + k4];
            *(uint4v*)&sW32[f2 * 68 + k4 * 4] = v;
        }
    } else {
        const float4* Wf4 = (const float4*)W;
        for (int i = tid; i < 128 * 16; i += nthr) {
            int f2 = i >> 4, k4 = i & 15;
            int base = ((woff + f2 * wstride) >> 2) + k4 * 2;
            float4 a = Wf4[base], b = Wf4[base + 1];
            uint4v v;
            v.x = (u32)bf16r(a.x) | ((u32)bf16r(a.y) << 16);
            v.y = (u32)bf16r(a.z) | ((u32)bf16r(a.w) << 16);
            v.z = (u32)bf16r(b.x) | ((u32)bf16r(b.y) << 16);
            v.w = (u32)bf16r(b.z) | ((u32)bf16r(b.w) << 16);
            *(uint4v*)&sW32[f2 * 68 + k4 * 4] = v;
        }
    }
}

// ---- MFMA node GEMM (R26 proven: GEMM2 x-loads hoisted):
//   x += silu(in@W2.T+b2)@Wl.T+bl ; if W1n: hb = bf16(x_new @ W1n.T) ----
__global__ __launch_bounds__(256) void k_mfma_lin(const u32* __restrict__ in,
                                                  const void* W2, int w2off,
                                                  const void* B2, int b2off,
                                                  const void* Wl, int wloff,
                                                  const void* Bl, int bloff,
                                                  const void* W1n, int w1noff,
                                                  float* x, u16* __restrict__ hb,
                                                  const void* means,
                                                  void* outp) {
    __shared__ u16 sW2[128 * 136];
    __shared__ u16 sWl[128 * 136];
    __shared__ u16 sW1[128 * 136];
    __shared__ u16 sA[4][16 * 136];
    __shared__ float sB2v[128], sBlv[128];
    int tid = threadIdx.x;
    int bf = bfflag(means);
    stage_w16(W2, w2off, H, sW2, tid, 256, bf);
    stage_w16(Wl, wloff, H, sWl, tid, 256, bf);
    if (W1n) stage_w16(W1n, w1noff, H, sW1, tid, 256, bf);
    if (tid < 128) {
        sB2v[tid] = ldf(B2, b2off + tid, bf);
        sBlv[tid] = ldf(Bl, bloff + tid, bf);
    }
    __syncthreads();
    int w = tid >> 6, lane = tid & 63;
    int quad = lane >> 4, l16 = lane & 15;
    u16* myA = sA[w];
    u32* myA32 = (u32*)myA;
    for (int tile = blockIdx.x * 4 + w; tile < NATOMS / 16; tile += gridDim.x * 4) {
        int abase = tile * 16;
        // hoisted GEMM2 x-reads: overlap A-staging + GEMM1
        float xv[8][4];
        #pragma unroll
        for (int nt = 0; nt < 8; ++nt) {
            int col = nt * 16 + l16;
            #pragma unroll
            for (int r = 0; r < 4; ++r)
                xv[nt][r] = x[(size_t)(abase + quad * 4 + r) * H + col];
        }
        const u32* in2 = in + (size_t)abase * 64;
        #pragma unroll 4
        for (int j = 0; j < 16; ++j)
            myA32[j * 68 + lane] = in2[j * 64 + lane];
        __asm__ volatile("s_waitcnt lgkmcnt(0)" ::: "memory");
        short8 af0 = *(const short8*)&myA[l16 * 136 +   0 + quad * 8];
        short8 af1 = *(const short8*)&myA[l16 * 136 +  32 + quad * 8];
        short8 af2 = *(const short8*)&myA[l16 * 136 +  64 + quad * 8];
        short8 af3 = *(const short8*)&myA[l16 * 136 +  96 + quad * 8];
        // GEMM 1: myA <- bf16(silu(in @ W2.T + b2))
        #pragma unroll 1
        for (int nt = 0; nt < 8; ++nt) {
            const u16* wrow = &sW2[(nt * 16 + l16) * 136];
            short8 b0 = *(const short8*)&wrow[0  + quad * 8];
            short8 b1 = *(const short8*)&wrow[32 + quad * 8];
            short8 b2 = *(const short8*)&wrow[64 + quad * 8];
            short8 b3 = *(const short8*)&wrow[96 + quad * 8];
            float4v acc = {0.f, 0.f, 0.f, 0.f};
            acc = __builtin_amdgcn_mfma_f32_16x16x32_bf16(af0, b0, acc, 0, 0, 0);
            acc = __builtin_amdgcn_mfma_f32_16x16x32_bf16(af1, b1, acc, 0, 0, 0);
            acc = __builtin_amdgcn_mfma_f32_16x16x32_bf16(af2, b2, acc, 0, 0, 0);
            acc = __builtin_amdgcn_mfma_f32_16x16x32_bf16(af3, b3, acc, 0, 0, 0);
            int col = nt * 16 + l16;
            float bias = sB2v[col];
            myA[(quad * 4 + 0) * 136 + col] = bf16r(silu_f(acc[0] + bias));
            myA[(quad * 4 + 1) * 136 + col] = bf16r(silu_f(acc[1] + bias));
            myA[(quad * 4 + 2) * 136 + col] = bf16r(silu_f(acc[2] + bias));
            myA[(quad * 4 + 3) * 136 + col] = bf16r(silu_f(acc[3] + bias));
        }
        __asm__ volatile("s_waitcnt lgkmcnt(0)" ::: "memory");
        short8 t0 = *(const short8*)&myA[l16 * 136 +   0 + quad * 8];
        short8 t1 = *(const short8*)&myA[l16 * 136 +  32 + quad * 8];
        short8 t2 = *(const short8*)&myA[l16 * 136 +  64 + quad * 8];
        short8 t3 = *(const short8*)&myA[l16 * 136 +  96 + quad * 8];
        // GEMM 2: x += t @ Wl.T + bl ; stash bf16(x_new) back to myA for GEMM 3
        #pragma unroll 1
        for (int nt = 0; nt < 8; ++nt) {
            const u16* wrow = &sWl[(nt * 16 + l16) * 136];
            short8 b0 = *(const short8*)&wrow[0  + quad * 8];
            short8 b1 = *(const short8*)&wrow[32 + quad * 8];
            short8 b2 = *(const short8*)&wrow[64 + quad * 8];
            short8 b3 = *(const short8*)&wrow[96 + quad * 8];
            int col = nt * 16 + l16;
            float bias = sBlv[col];
            float4v acc;
            acc[0] = xv[nt][0] + bias;
            acc[1] = xv[nt][1] + bias;
            acc[2] = xv[nt][2] + bias;
            acc[3] = xv[nt][3] + bias;
            acc = __builtin_amdgcn_mfma_f32_16x16x32_bf16(t0, b0, acc, 0, 0, 0);
            acc = __builtin_amdgcn_mfma_f32_16x16x32_bf16(t1, b1, acc, 0, 0, 0);
            acc = __builtin_amdgcn_mfma_f32_16x16x32_bf16(t2, b2, acc, 0, 0, 0);
            acc = __builtin_amdgcn_mfma_f32_16x16x32_bf16(t3, b3, acc, 0, 0, 0);
            #pragma unroll
            for (int r = 0; r < 4; ++r) {
                size_t idx = (size_t)(abase + quad * 4 + r) * H + col;
                x[idx] = acc[r];
                myA[(quad * 4 + r) * 136 + col] = bf16r(acc[r]);
                if (outp) {
                    if (bf) ((u16*)outp)[idx] = bf16r(acc[r]);
                    else    ((float*)outp)[idx] = acc[r];
                }
            }
        }
        // GEMM 3 (fused next-layer lin1): hb = bf16(x_new @ W1n.T), no bias
        if (W1n) {
            __asm__ volatile("s_waitcnt lgkmcnt(0)" ::: "memory");
            short8 h0 = *(const short8*)&myA[l16 * 136 +   0 + quad * 8];
            short8 h1 = *(const short8*)&myA[l16 * 136 +  32 + quad * 8];
            short8 h2 = *(const short8*)&myA[l16 * 136 +  64 + quad * 8];
            short8 h3 = *(const short8*)&myA[l16 * 136 +  96 + quad * 8];
            #pragma unroll 1
            for (int nt = 0; nt < 8; ++nt) {
                const u16* wrow = &sW1[(nt * 16 + l16) * 136];
                short8 b0 = *(const short8*)&wrow[0  + quad * 8];
                short8 b1 = *(const short8*)&wrow[32 + quad * 8];
                short8 b2 = *(const short8*)&wrow[64 + quad * 8];
                short8 b3 = *(const short8*)&wrow[96 + quad * 8];
                float4v acc = {0.f, 0.f, 0.f, 0.f};
                acc = __builtin_amdgcn_mfma_f32_16x16x32_bf16(h0, b0, acc, 0, 0, 0);
                acc = __builtin_amdgcn_mfma_f32_16x16x32_bf16(h1, b1, acc, 0, 0, 0);
                acc = __builtin_amdgcn_mfma_f32_16x16x32_bf16(h2, b2, acc, 0, 0, 0);
                acc = __builtin_amdgcn_mfma_f32_16x16x32_bf16(h3, b3, acc, 0, 0, 0);
                int col = nt * 16 + l16;
                hb[(size_t)(abase + quad * 4 + 0) * H + col] = bf16r(acc[0]);
                hb[(size_t)(abase + quad * 4 + 1) * H + col] = bf16r(acc[1]);
                hb[(size_t)(abase + quad * 4 + 2) * H + col] = bf16r(acc[2]);
                hb[(size_t)(abase + quad * 4 + 3) * H + col] = bf16r(acc[3]);
            }
        }
    }
}

// ---- MFMA NE combine (R23 proven); also hb = bf16(x @ l1w0.T) ----
__global__ __launch_bounds__(256) void k_mfma_comb(const float* in0, const u32* __restrict__ in1,
                                                   const void* W, const void* B,
                                                   const void* W1,
                                                   float* x, u16* __restrict__ hb,
                                                   const void* means) {
    __shared__ u16 sWa[128 * 136];
    __shared__ u16 sWb[128 * 136];
    __shared__ u16 sW1[128 * 136];
    __shared__ u16 sA[4][16 * 136];
    __shared__ float sBv[128];
    int tid = threadIdx.x;
    int bf = bfflag(means);
    stage_w16(W, 0,   256, sWa, tid, 256, bf);
    stage_w16(W, 128, 256, sWb, tid, 256, bf);
    stage_w16(W1, 0, H, sW1, tid, 256, bf);
    if (tid < 128) sBv[tid] = ldf(B, tid, bf);
    __syncthreads();
    int w = tid >> 6, lane = tid & 63;
    int quad = lane >> 4, l16 = lane & 15;
    u16* myA = sA[w];
    u32* myA32 = (u32*)myA;
    for (int tile = blockIdx.x * 4 + w; tile < NATOMS / 16; tile += gridDim.x * 4) {
        int abase = tile * 16;
        const float2* i0 = (const float2*)in0 + (size_t)abase * 64;
        const u32* i1 = in1 + (size_t)abase * 64;
        #pragma unroll 4
        for (int j = 0; j < 16; ++j) {
            float2 v = i0[j * 64 + lane];
            myA32[j * 68 + lane] = (u32)bf16r(v.x) | ((u32)bf16r(v.y) << 16);
        }
        __asm__ volatile("s_waitcnt lgkmcnt(0)" ::: "memory");
        short8 af0 = *(const short8*)&myA[l16 * 136 +   0 + quad * 8];
        short8 af1 = *(const short8*)&myA[l16 * 136 +  32 + quad * 8];
        short8 af2 = *(const short8*)&myA[l16 * 136 +  64 + quad * 8];
        short8 af3 = *(const short8*)&myA[l16 * 136 +  96 + quad * 8];
        #pragma unroll 4
        for (int j = 0; j < 16; ++j)
            myA32[j * 68 + lane] = i1[j * 64 + lane];
        __asm__ volatile("s_waitcnt lgkmcnt(0)" ::: "memory");
        short8 ag0 = *(const short8*)&myA[l16 * 136 +   0 + quad * 8];
        short8 ag1 = *(const short8*)&myA[l16 * 136 +  32 + quad * 8];
        short8 ag2 = *(const short8*)&myA[l16 * 136 +  64 + quad * 8];
        short8 ag3 = *(const short8*)&myA[l16 * 136 +  96 + quad * 8];
        #pragma unroll 1
        for (int nt = 0; nt < 8; ++nt) {
            const u16* wra = &sWa[(nt * 16 + l16) * 136];
            const u16* wrb = &sWb[(nt * 16 + l16) * 136];
            int col = nt * 16 + l16;
            float bias = sBv[col];
            float4v acc = {bias, bias, bias, bias};
            acc = __builtin_amdgcn_mfma_f32_16x16x32_bf16(af0, *(const short8*)&wra[0  + quad * 8], acc, 0, 0, 0);
            acc = __builtin_amdgcn_mfma_f32_16x16x32_bf16(af1, *(const short8*)&wra[32 + quad * 8], acc, 0, 0, 0);
            acc = __builtin_amdgcn_mfma_f32_16x16x32_bf16(af2, *(const short8*)&wra[64 + quad * 8], acc, 0, 0, 0);
            acc = __builtin_amdgcn_mfma_f32_16x16x32_bf16(af3, *(const short8*)&wra[96 + quad * 8], acc, 0, 0, 0);
            acc = __builtin_amdgcn_mfma_f32_16x16x32_bf16(ag0, *(const short8*)&wrb[0  + quad * 8], acc, 0, 0, 0);
            acc = __builtin_amdgcn_mfma_f32_16x16x32_bf16(ag1, *(const short8*)&wrb[32 + quad * 8], acc, 0, 0, 0);
            acc = __builtin_amdgcn_mfma_f32_16x16x32_bf16(ag2, *(const short8*)&wrb[64 + quad * 8], acc, 0, 0, 0);
            acc = __builtin_amdgcn_mfma_f32_16x16x32_bf16(ag3, *(const short8*)&wrb[96 + quad * 8], acc, 0, 0, 0);
            #pragma unroll
            for (int r = 0; r < 4; ++r) {
                x[(size_t)(abase + quad * 4 + r) * H + col] = acc[r];
                myA[(quad * 4 + r) * 136 + col] = bf16r(acc[r]);
            }
        }
        // fused layer-0 lin1: hb = bf16(x @ l1w0.T)
        __asm__ volatile("s_waitcnt lgkmcnt(0)" ::: "memory");
        short8 h0 = *(const short8*)&myA[l16 * 136 +   0 + quad * 8];
        short8 h1 = *(const short8*)&myA[l16 * 136 +  32 + quad * 8];
        short8 h2 = *(const short8*)&myA[l16 * 136 +  64 + quad * 8];
        short8 h3 = *(const short8*)&myA[l16 * 136 +  96 + quad * 8];
        #pragma unroll 1
        for (int nt = 0; nt < 8; ++nt) {
            const u16* wrow = &sW1[(nt * 16 + l16) * 136];
            short8 b0 = *(const short8*)&wrow[0  + quad * 8];
            short8 b1 = *(const short8*)&wrow[32 + quad * 8];
            short8 b2 = *(const short8*)&wrow[64 + quad * 8];
            short8 b3 = *(const short8*)&wrow[96 + quad * 8];
            float4v acc = {0.f, 0.f, 0.f, 0.f};
            acc = __builtin_amdgcn_mfma_f32_16x16x32_bf16(h0, b0, acc, 0, 0, 0);
            acc = __builtin_amdgcn_mfma_f32_16x16x32_bf16(h1, b1, acc, 0, 0, 0);
            acc = __builtin_amdgcn_mfma_f32_16x16x32_bf16(h2, b2, acc, 0, 0, 0);
            acc = __builtin_amdgcn_mfma_f32_16x16x32_bf16(h3, b3, acc, 0, 0, 0);
            int col = nt * 16 + l16;
            hb[(size_t)(abase + quad * 4 + 0) * H + col] = bf16r(acc[0]);
            hb[(size_t)(abase + quad * 4 + 1) * H + col] = bf16r(acc[1]);
            hb[(size_t)(abase + quad * 4 + 2) * H + col] = bf16r(acc[2]);
            hb[(size_t)(abase + quad * 4 + 3) * H + col] = bf16r(acc[3]);
        }
    }
}

// ---- R27 merged: blocks 0-511 = 4 tables (R25 NT=2048 form), blocks 512-824
//      = CSR scatter (R21 form). Both need only rs/cnt (previous kernels). ----
__global__ __launch_bounds__(1024) void k_ft4_scatter(const void* means, const void* betas,
                                                      const void* W0s, const void* B0s,
                                                      const void* W1s, const void* B1s,
                                                      const void* Wne, const void* Bne,
                                                      u16* __restrict__ ftT,
                                                      u16* __restrict__ Tne,
                                                      const int* __restrict__ src,
                                                      const int* __restrict__ dst,
                                                      const void* ew,
                                                      const int* __restrict__ rs,
                                                      int* __restrict__ cnt,
                                                      uint2* __restrict__ ed) {
    int tid = threadIdx.x;
    int bf = bfflag(means);
    if (blockIdx.x >= 512) {   // scatter: build CSR edge data
        int e = (blockIdx.x - 512) * 1024 + tid;
        if (e < NEDGES) {
            int s = src[e];
            int p = rs[s] + atomicAdd(&cnt[s], 1);
            float u = ldf(ew, e, bf) * ((float)(NT - 1) / 5.0f);   // pre-scaled
            ed[p] = make_uint2((u32)dst[e], __float_as_uint(u));
        }
        return;
    }
    __shared__ float sW0[H * 53];
    __shared__ u16 sW1b[128 * 136];
    __shared__ u16 sA16[16 * 136];
    __shared__ float sR[16][56];
    __shared__ float sM[NRBF], sBe[NRBF], sB1v[128], sC[16];
    int t = blockIdx.x >> 7;                 // 0..2 = layer filter, 3 = NE table
    int bb = blockIdx.x & 127;               // 128 blocks per table (NT/16)
    int ne = (t == 3);
    const void* W0 = ne ? Wne : W0s;
    int w0off = ne ? 0 : t * H * NRBF;
    u16* T = ne ? Tne : (ftT + (size_t)t * NT * H);
    if (!ne) stage_w16(W1s, t * H * H, H, sW1b, tid, 1024, bf);
    for (int i = tid; i < H * NRBF; i += 1024) {
        int f2 = i / NRBF, k = i - f2 * NRBF;
        sW0[f2 * 53 + k] = ldf(W0, w0off + i, bf);
    }
    if (tid < NRBF) { sM[tid] = ldf(means, tid, bf); sBe[tid] = ldf(betas, tid, bf); }
    if (tid < 128) sB1v[tid] = ne ? 0.f : ldf(B1s, t * H + tid, bf);
    __syncthreads();
    int g = tid >> 7, f = tid & 127;
    float b0r = ne ? ldf(Bne, f, bf) : ldf(B0s, t * H + f, bf);
    int base = bb * 16;
    int n0 = base + 2 * g, n1 = n0 + 1;
    float wv0 = (float)n0 * (5.0f / (NT - 1));
    float wv1 = (float)n1 * (5.0f / (NT - 1));
    if (f < NRBF) {
        float tt = expf(-wv0) - sM[f];
        sR[2 * g][f] = expf(-sBe[f] * tt * tt);
    } else if (f >= 64 && f < 64 + NRBF) {
        float tt = expf(-wv1) - sM[f - 64];
        sR[2 * g + 1][f - 64] = expf(-sBe[f - 64] * tt * tt);
    }
    __syncthreads();
    float c0 = 0.5f * (cosf(wv0 * 0.62831853071795864f) + 1.f); if (!(wv0 < 5.f)) c0 = 0.f;
    float c1 = 0.5f * (cosf(wv1 * 0.62831853071795864f) + 1.f); if (!(wv1 < 5.f)) c1 = 0.f;
    if (f == 0) { sC[2 * g] = c0; sC[2 * g + 1] = c1; }
    float s0 = 0.f, s1 = 0.f;
    #pragma unroll
    for (int k = 0; k < NRBF; ++k) {
        float wk = sW0[f * 53 + k];
        s0 = fmaf(wk, sR[2 * g][k], s0);
        s1 = fmaf(wk, sR[2 * g + 1][k], s1);
    }
    if (ne) {   // NE table: T = (c*acc + b)*c — block-uniform branch, safe return
        T[(size_t)n0 * H + f] = bf16r(fmaf(c0, s0, b0r) * c0);
        T[(size_t)n1 * H + f] = bf16r(fmaf(c1, s1, b0r) * c1);
        return;
    }
    sA16[(2 * g) * 136 + f]     = bf16r(silu_f(fmaf(c0, s0, b0r)));
    sA16[(2 * g + 1) * 136 + f] = bf16r(silu_f(fmaf(c1, s1, b0r)));
    __syncthreads();
    int w = tid >> 6;
    if (w < 8) {
        int lane = tid & 63;
        int quad = lane >> 4, l16 = lane & 15;
        short8 a0 = *(const short8*)&sA16[l16 * 136 +   0 + quad * 8];
        short8 a1 = *(const short8*)&sA16[l16 * 136 +  32 + quad * 8];
        short8 a2 = *(const short8*)&sA16[l16 * 136 +  64 + quad * 8];
        short8 a3 = *(const short8*)&sA16[l16 * 136 +  96 + quad * 8];
        const u16* wrow = &sW1b[(w * 16 + l16) * 136];
        short8 b0 = *(const short8*)&wrow[0  + quad * 8];
        short8 b1 = *(const short8*)&wrow[32 + quad * 8];
        short8 b2 = *(const short8*)&wrow[64 + quad * 8];
        short8 b3 = *(const short8*)&wrow[96 + quad * 8];
        float4v acc = {0.f, 0.f, 0.f, 0.f};
        acc = __builtin_amdgcn_mfma_f32_16x16x32_bf16(a0, b0, acc, 0, 0, 0);
        acc = __builtin_amdgcn_mfma_f32_16x16x32_bf16(a1, b1, acc, 0, 0, 0);
        acc = __builtin_amdgcn_mfma_f32_16x16x32_bf16(a2, b2, acc, 0, 0, 0);
        acc = __builtin_amdgcn_mfma_f32_16x16x32_bf16(a3, b3, acc, 0, 0, 0);
        int col = w * 16 + l16;
        float bias = sB1v[col];
        #pragma unroll
        for (int r = 0; r < 4; ++r) {
            int row = quad * 4 + r;
            T[(size_t)(base + row) * H + col] = bf16r((acc[r] + bias) * sC[row]);
        }
    }
}

// ---- R21: GATHER edge aggregation — one wave per atom, CSR walk, zero atomics.
#define GEV(i) \
    uint2 ed##i = ed[e + i]; \
    int d##i = (int)ed##i.x; float u##i = __uint_as_float(ed##i.y); \
    int ix##i = min((int)u##i, NT - 2); float fr##i = u##i - (float)ix##i; \
    u32 ta##i = Tb[ix##i * 64 + lane], tb##i = Tb[ix##i * 64 + 64 + lane]; \
    u32 h##i = vh[d##i * 64 + lane]; \
    float vx##i = fmaf(fr##i, bfu((u16)(tb##i & 0xffff)) - bfu((u16)(ta##i & 0xffff)), bfu((u16)(ta##i & 0xffff))) * bfu((u16)(h##i & 0xffff)); \
    float vy##i = fmaf(fr##i, bfu((u16)(tb##i >> 16))    - bfu((u16)(ta##i >> 16)),    bfu((u16)(ta##i >> 16)))    * bfu((u16)(h##i >> 16));
#define GACC(i) \
    if (!(mask_self && d##i == s)) { rx += vx##i; ry += vy##i; }

__global__ __launch_bounds__(256) void k_edge_gather(const int* __restrict__ rs,
                                                     const uint2* __restrict__ ed,
                                                     const u32* __restrict__ Tb,
                                                     const u32* __restrict__ vh,
                                                     u32* __restrict__ accb,
                                                     int mask_self) {
    int tid = threadIdx.x;
    int g = tid >> 6, lane = tid & 63;
    int s = blockIdx.x * 4 + g;          // 2500 blocks x 4 waves = 10000 atoms
    if (s >= NATOMS) return;
    int e0 = rs[s];
    int e1 = (s < NATOMS - 1) ? rs[s + 1] : NEDGES;
    float rx = 0.f, ry = 0.f;
    int e = e0;
    for (; e + 8 <= e1; e += 8) {
        GEV(0) GEV(1) GEV(2) GEV(3) GEV(4) GEV(5) GEV(6) GEV(7)
        GACC(0) GACC(1) GACC(2) GACC(3) GACC(4) GACC(5) GACC(6) GACC(7)
    }
    for (; e < e1; ++e) {
        uint2 edt = ed[e];
        int dt = (int)edt.x; float ut = __uint_as_float(edt.y);
        int ixt = min((int)ut, NT - 2); float frt = ut - (float)ixt;
        u32 tat = Tb[ixt * 64 + lane], tbt = Tb[ixt * 64 + 64 + lane];
        u32 ht = vh[dt * 64 + lane];
        float vxt = fmaf(frt, bfu((u16)(tbt & 0xffff)) - bfu((u16)(tat & 0xffff)), bfu((u16)(tat & 0xffff))) * bfu((u16)(ht & 0xffff));
        float vyt = fmaf(frt, bfu((u16)(tbt >> 16))    - bfu((u16)(tat >> 16)),    bfu((u16)(tat >> 16)))    * bfu((u16)(ht >> 16));
        if (!(mask_self && dt == s)) { rx += vxt; ry += vyt; }
    }
    accb[(size_t)s * 64 + lane] = (u32)bf16r(rx) | ((u32)bf16r(ry) << 16);
}

extern "C" void kernel_launch(void* const* d_in, const int* in_sizes, int n_in,
                              void* d_out, int out_size, void* d_ws, size_t ws_size,
                              hipStream_t stream) {
    const int* z  = (const int*)d_in[0];
    const int* ei = (const int*)d_in[1];
    const void* ew        = d_in[2];
    const void* emb       = d_in[3];
    const void* means     = d_in[4];
    const void* betas     = d_in[5];
    const void* ne_proj_w = d_in[6];
    const void* ne_proj_b = d_in[7];
    const void* ne_comb_w = d_in[8];
    const void* ne_comb_b = d_in[9];
    const void* mlp_w0    = d_in[10];
    const void* mlp_b0    = d_in[11];
    const void* mlp_w1    = d_in[12];
    const void* mlp_b1    = d_in[13];
    const void* lin1_w    = d_in[14];
    const void* lin2_w    = d_in[15];
    const void* lin2_b    = d_in[16];
    const void* lin_w     = d_in[17];
    const void* lin_b     = d_in[18];

    const int* srcp = ei;
    const int* dstp = ei + NEDGES;

    float* buf0 = (float*)d_ws;            // x0 fp32
    float* x    = buf0 + NELEM;            // persistent fp32 node state
    u32*   accb = (u32*)(x + NELEM);       // bf16x2 gather accumulator (NELEM/2 u32)
    int*   deg  = (int*)(accb + NELEM / 2);// deg[10240] + cnt[10240]
    int*   cnt  = deg + 10240;
    int*   rs   = cnt + 10240;
    uint2* ed   = (uint2*)(rs + 10240);    // CSR edge data {dst, ew bits}
    u16*   Tb   = (u16*)(ed + NEDGES);     // NE table, NT x 128 bf16 (0.5MB)
    u16*   hb   = Tb + NT * H;             // bf16 h / x0 mirror
    u16*   ftT  = hb + NELEM;              // 3 filter tables (3 x 0.5MB)

    const int gEdge = (NEDGES + 255) / 256;

    // zero deg+cnt (capture-legal fill node; replaces embed's zero pass)
    hipMemsetAsync(deg, 0, 20480 * sizeof(int), stream);

    // counting sort histogram
    k_hist<<<gEdge, 256, 0, stream>>>(srcp, deg);

    // embed (blocks 0-312) || scan (block 313)
    k_embed_scan<<<314, 1024, 0, stream>>>(z, emb, means, buf0, hb, deg, rs);

    // 4 tables (blocks 0-511) || CSR scatter (blocks 512-824)
    k_ft4_scatter<<<825, 1024, 0, stream>>>(means, betas, mlp_w0, mlp_b0,
                                            mlp_w1, mlp_b1, ne_proj_w, ne_proj_b,
                                            ftT, Tb, srcp, dstp, ew, rs, cnt, ed);

    // NeighborEmbedding edge pass (gather, no atomics)
    k_edge_gather<<<2500, 256, 0, stream>>>(rs, ed, (const u32*)Tb,
                                            (const u32*)hb, accb, 1);
    // combine + fused layer-0 lin1 (writes x and hb)
    k_mfma_comb<<<256, 256, 0, stream>>>(buf0, accb, ne_comb_w, ne_comb_b,
                                         lin1_w, x, hb, means);

    for (int L = 0; L < 3; ++L) {
        k_edge_gather<<<2500, 256, 0, stream>>>(rs, ed,
                                                (const u32*)(ftT + (size_t)L * NT * H),
                                                (const u32*)hb, accb, 0);
        // x += silu(a@l2w.T+b2)@lw.T + lb ; fused next-layer lin1 -> hb;
        // last layer writes d_out
        k_mfma_lin<<<256, 256, 0, stream>>>(accb, lin2_w, L * H * H, lin2_b, L * H,
                                            lin_w, L * H * H, lin_b, L * H,
                                            (L < 2) ? lin1_w : nullptr, (L + 1) * H * H,
                                            x, hb, means,
                                            (L == 2) ? d_out : nullptr);
    }
}

// Round 11
// 306.147 us; speedup vs baseline: 1.1020x; 1.0045x over previous
//
#include <hip/hip_runtime.h>
#include <hip/hip_bf16.h>

#define NATOMS 10000
#define NEDGES 320000
#define H 128
#define NRBF 50
#define NELEM (NATOMS * H)
#define NT 2048

typedef unsigned short u16;
typedef unsigned int u32;
typedef __attribute__((ext_vector_type(8))) short short8;
typedef __attribute__((ext_vector_type(4))) float float4v;
typedef __attribute__((ext_vector_type(4))) unsigned int uint4v;

__device__ __forceinline__ float bfu(u16 u) { return __uint_as_float(((u32)u) << 16); }
__device__ __forceinline__ u16 bf16r(float v) {   // RNE
    u32 u = __float_as_uint(v);
    return (u16)((u + 0x7FFFu + ((u >> 16) & 1u)) >> 16);
}
__device__ __forceinline__ float ldf(const void* p, int i, int bf) {
    return bf ? bfu(((const u16*)p)[i]) : ((const float*)p)[i];
}
__device__ __forceinline__ float silu_f(float v) { return v / (1.f + __expf(-v)); }
// inline dtype detect (proven logic r3-r17): means[49]==1.0 -> bf16 word24 hi = 0x3F80
__device__ __forceinline__ int bfflag(const void* means) {
    return ((((const u32*)means)[24] >> 16) == 0x3F80u) ? 1 : 0;
}

// ---- counting sort: histogram by src (proven) ----
__global__ __launch_bounds__(256) void k_hist(const int* __restrict__ src, int* __restrict__ deg) {
    int e = blockIdx.x * 256 + threadIdx.x;
    if (e < NEDGES) atomicAdd(&deg[src[e]], 1);
}

// ---- R28: embed writes ONLY the bf16 mirror xh (fp32 x0 eliminated — comb
//      reads hb raw, bit-identical). blocks 0-312 = embed, block 313 = scan. ----
__global__ __launch_bounds__(1024) void k_embed_scan(const int* __restrict__ z, const void* emb,
                                                     const void* means,
                                                     u16* __restrict__ xh,
                                                     const int* __restrict__ deg,
                                                     int* __restrict__ rs) {
    int tid = threadIdx.x;
    if (blockIdx.x == 313) {   // shuffle-based exclusive scan, 3 barriers
        __shared__ int wsum[16];
        int lane = tid & 63, w = tid >> 6;
        int d[10];
        int tot = 0;
        int base_i = tid * 10;
        if (tid < 1000) {
            #pragma unroll
            for (int j = 0; j < 10; ++j) d[j] = deg[base_i + j];
            #pragma unroll
            for (int j = 0; j < 10; ++j) { int v = d[j]; d[j] = tot; tot += v; }
        }
        int inc = tot;
        #pragma unroll
        for (int off = 1; off < 64; off <<= 1) {
            int n = __shfl_up(inc, off, 64);
            if (lane >= off) inc += n;
        }
        if (lane == 63) wsum[w] = inc;
        __syncthreads();
        if (w == 0) {
            int v = (lane < 16) ? wsum[lane] : 0;
            int vinc = v;
            #pragma unroll
            for (int off = 1; off < 16; off <<= 1) {
                int n = __shfl_up(vinc, off, 64);
                if (lane >= off) vinc += n;
            }
            if (lane < 16) wsum[lane] = vinc - v;   // exclusive wave offsets
        }
        __syncthreads();
        if (tid < 1000) {
            int base = wsum[w] + (inc - tot);
            #pragma unroll
            for (int j = 0; j < 10; ++j) rs[base_i + j] = base + d[j];
        }
        return;
    }
    // embed: bf16 mirror only, 4 elems/thread
    int bf = bfflag(means);
    int t = blockIdx.x * 1024 + tid;             // 0 .. NELEM/4-1
    if (t < NELEM / 4) {
        int n = t >> 5, f4 = (t & 31) * 4;       // 32 threads per atom row
        if (bf) {
            uint2 raw = *(const uint2*)((const u16*)emb + (size_t)z[n] * H + f4);
            *(uint2*)&xh[(size_t)n * H + f4] = raw;   // exact bf16 roundtrip
        } else {
            float4 v = *(const float4*)((const float*)emb + (size_t)z[n] * H + f4);
            uint2 p;
            p.x = (u32)bf16r(v.x) | ((u32)bf16r(v.y) << 16);
            p.y = (u32)bf16r(v.z) | ((u32)bf16r(v.w) << 16);
            *(uint2*)&xh[(size_t)n * H + f4] = p;
        }
    }
}

// ---- bf16 LDS weight staging for MFMA: row stride 136 u16 (68 u32).
// R23 proven: 16B vector loads + 16B LDS writes (row byte stride 272 = 17*16).
__device__ __forceinline__ void stage_w16(const void* W, int woff, int wstride,
                                          u16* sW, int tid, int nthr, int bf) {
    u32* sW32 = (u32*)sW;
    if (bf) {
        const uint4v* W4 = (const uint4v*)W;     // 8 bf16 per uint4
        for (int i = tid; i < 128 * 16; i += nthr) {
            int f2 = i >> 4, k4 = i & 15;
            uint4v v = W4[((woff + f2 * wstride) >> 3) + k4];
            *(uint4v*)&sW32[f2 * 68 + k4 * 4] = v;
        }
    } else {
        const float4* Wf4 = (const float4*)W;
        for (int i = tid; i < 128 * 16; i += nthr) {
            int f2 = i >> 4, k4 = i & 15;
            int base = ((woff + f2 * wstride) >> 2) + k4 * 2;
            float4 a = Wf4[base], b = Wf4[base + 1];
            uint4v v;
            v.x = (u32)bf16r(a.x) | ((u32)bf16r(a.y) << 16);
            v.y = (u32)bf16r(a.z) | ((u32)bf16r(a.w) << 16);
            v.z = (u32)bf16r(b.x) | ((u32)bf16r(b.y) << 16);
            v.w = (u32)bf16r(b.z) | ((u32)bf16r(b.w) << 16);
            *(uint4v*)&sW32[f2 * 68 + k4 * 4] = v;
        }
    }
}

// ---- MFMA node GEMM (R26 proven: GEMM2 x-loads hoisted):
//   x += silu(in@W2.T+b2)@Wl.T+bl ; if W1n: hb = bf16(x_new @ W1n.T) ----
__global__ __launch_bounds__(256) void k_mfma_lin(const u32* __restrict__ in,
                                                  const void* W2, int w2off,
                                                  const void* B2, int b2off,
                                                  const void* Wl, int wloff,
                                                  const void* Bl, int bloff,
                                                  const void* W1n, int w1noff,
                                                  float* x, u16* __restrict__ hb,
                                                  const void* means,
                                                  void* outp) {
    __shared__ u16 sW2[128 * 136];
    __shared__ u16 sWl[128 * 136];
    __shared__ u16 sW1[128 * 136];
    __shared__ u16 sA[4][16 * 136];
    __shared__ float sB2v[128], sBlv[128];
    int tid = threadIdx.x;
    int bf = bfflag(means);
    stage_w16(W2, w2off, H, sW2, tid, 256, bf);
    stage_w16(Wl, wloff, H, sWl, tid, 256, bf);
    if (W1n) stage_w16(W1n, w1noff, H, sW1, tid, 256, bf);
    if (tid < 128) {
        sB2v[tid] = ldf(B2, b2off + tid, bf);
        sBlv[tid] = ldf(Bl, bloff + tid, bf);
    }
    __syncthreads();
    int w = tid >> 6, lane = tid & 63;
    int quad = lane >> 4, l16 = lane & 15;
    u16* myA = sA[w];
    u32* myA32 = (u32*)myA;
    for (int tile = blockIdx.x * 4 + w; tile < NATOMS / 16; tile += gridDim.x * 4) {
        int abase = tile * 16;
        // hoisted GEMM2 x-reads: overlap A-staging + GEMM1
        float xv[8][4];
        #pragma unroll
        for (int nt = 0; nt < 8; ++nt) {
            int col = nt * 16 + l16;
            #pragma unroll
            for (int r = 0; r < 4; ++r)
                xv[nt][r] = x[(size_t)(abase + quad * 4 + r) * H + col];
        }
        const u32* in2 = in + (size_t)abase * 64;
        #pragma unroll 4
        for (int j = 0; j < 16; ++j)
            myA32[j * 68 + lane] = in2[j * 64 + lane];
        __asm__ volatile("s_waitcnt lgkmcnt(0)" ::: "memory");
        short8 af0 = *(const short8*)&myA[l16 * 136 +   0 + quad * 8];
        short8 af1 = *(const short8*)&myA[l16 * 136 +  32 + quad * 8];
        short8 af2 = *(const short8*)&myA[l16 * 136 +  64 + quad * 8];
        short8 af3 = *(const short8*)&myA[l16 * 136 +  96 + quad * 8];
        // GEMM 1: myA <- bf16(silu(in @ W2.T + b2))
        #pragma unroll 1
        for (int nt = 0; nt < 8; ++nt) {
            const u16* wrow = &sW2[(nt * 16 + l16) * 136];
            short8 b0 = *(const short8*)&wrow[0  + quad * 8];
            short8 b1 = *(const short8*)&wrow[32 + quad * 8];
            short8 b2 = *(const short8*)&wrow[64 + quad * 8];
            short8 b3 = *(const short8*)&wrow[96 + quad * 8];
            float4v acc = {0.f, 0.f, 0.f, 0.f};
            acc = __builtin_amdgcn_mfma_f32_16x16x32_bf16(af0, b0, acc, 0, 0, 0);
            acc = __builtin_amdgcn_mfma_f32_16x16x32_bf16(af1, b1, acc, 0, 0, 0);
            acc = __builtin_amdgcn_mfma_f32_16x16x32_bf16(af2, b2, acc, 0, 0, 0);
            acc = __builtin_amdgcn_mfma_f32_16x16x32_bf16(af3, b3, acc, 0, 0, 0);
            int col = nt * 16 + l16;
            float bias = sB2v[col];
            myA[(quad * 4 + 0) * 136 + col] = bf16r(silu_f(acc[0] + bias));
            myA[(quad * 4 + 1) * 136 + col] = bf16r(silu_f(acc[1] + bias));
            myA[(quad * 4 + 2) * 136 + col] = bf16r(silu_f(acc[2] + bias));
            myA[(quad * 4 + 3) * 136 + col] = bf16r(silu_f(acc[3] + bias));
        }
        __asm__ volatile("s_waitcnt lgkmcnt(0)" ::: "memory");
        short8 t0 = *(const short8*)&myA[l16 * 136 +   0 + quad * 8];
        short8 t1 = *(const short8*)&myA[l16 * 136 +  32 + quad * 8];
        short8 t2 = *(const short8*)&myA[l16 * 136 +  64 + quad * 8];
        short8 t3 = *(const short8*)&myA[l16 * 136 +  96 + quad * 8];
        // GEMM 2: x += t @ Wl.T + bl ; stash bf16(x_new) back to myA for GEMM 3
        #pragma unroll 1
        for (int nt = 0; nt < 8; ++nt) {
            const u16* wrow = &sWl[(nt * 16 + l16) * 136];
            short8 b0 = *(const short8*)&wrow[0  + quad * 8];
            short8 b1 = *(const short8*)&wrow[32 + quad * 8];
            short8 b2 = *(const short8*)&wrow[64 + quad * 8];
            short8 b3 = *(const short8*)&wrow[96 + quad * 8];
            int col = nt * 16 + l16;
            float bias = sBlv[col];
            float4v acc;
            acc[0] = xv[nt][0] + bias;
            acc[1] = xv[nt][1] + bias;
            acc[2] = xv[nt][2] + bias;
            acc[3] = xv[nt][3] + bias;
            acc = __builtin_amdgcn_mfma_f32_16x16x32_bf16(t0, b0, acc, 0, 0, 0);
            acc = __builtin_amdgcn_mfma_f32_16x16x32_bf16(t1, b1, acc, 0, 0, 0);
            acc = __builtin_amdgcn_mfma_f32_16x16x32_bf16(t2, b2, acc, 0, 0, 0);
            acc = __builtin_amdgcn_mfma_f32_16x16x32_bf16(t3, b3, acc, 0, 0, 0);
            #pragma unroll
            for (int r = 0; r < 4; ++r) {
                size_t idx = (size_t)(abase + quad * 4 + r) * H + col;
                x[idx] = acc[r];
                myA[(quad * 4 + r) * 136 + col] = bf16r(acc[r]);
                if (outp) {
                    if (bf) ((u16*)outp)[idx] = bf16r(acc[r]);
                    else    ((float*)outp)[idx] = acc[r];
                }
            }
        }
        // GEMM 3 (fused next-layer lin1): hb = bf16(x_new @ W1n.T), no bias
        if (W1n) {
            __asm__ volatile("s_waitcnt lgkmcnt(0)" ::: "memory");
            short8 h0 = *(const short8*)&myA[l16 * 136 +   0 + quad * 8];
            short8 h1 = *(const short8*)&myA[l16 * 136 +  32 + quad * 8];
            short8 h2 = *(const short8*)&myA[l16 * 136 +  64 + quad * 8];
            short8 h3 = *(const short8*)&myA[l16 * 136 +  96 + quad * 8];
            #pragma unroll 1
            for (int nt = 0; nt < 8; ++nt) {
                const u16* wrow = &sW1[(nt * 16 + l16) * 136];
                short8 b0 = *(const short8*)&wrow[0  + quad * 8];
                short8 b1 = *(const short8*)&wrow[32 + quad * 8];
                short8 b2 = *(const short8*)&wrow[64 + quad * 8];
                short8 b3 = *(const short8*)&wrow[96 + quad * 8];
                float4v acc = {0.f, 0.f, 0.f, 0.f};
                acc = __builtin_amdgcn_mfma_f32_16x16x32_bf16(h0, b0, acc, 0, 0, 0);
                acc = __builtin_amdgcn_mfma_f32_16x16x32_bf16(h1, b1, acc, 0, 0, 0);
                acc = __builtin_amdgcn_mfma_f32_16x16x32_bf16(h2, b2, acc, 0, 0, 0);
                acc = __builtin_amdgcn_mfma_f32_16x16x32_bf16(h3, b3, acc, 0, 0, 0);
                int col = nt * 16 + l16;
                hb[(size_t)(abase + quad * 4 + 0) * H + col] = bf16r(acc[0]);
                hb[(size_t)(abase + quad * 4 + 1) * H + col] = bf16r(acc[1]);
                hb[(size_t)(abase + quad * 4 + 2) * H + col] = bf16r(acc[2]);
                hb[(size_t)(abase + quad * 4 + 3) * H + col] = bf16r(acc[3]);
            }
        }
    }
}

// ---- MFMA NE combine (R28: i0 read raw from hb — bit-identical to old
//      fp32->bf16 convert; per-tile hb read precedes hb write, same wave) ----
__global__ __launch_bounds__(256) void k_mfma_comb(const u32* __restrict__ in0b,
                                                   const u32* __restrict__ in1,
                                                   const void* W, const void* B,
                                                   const void* W1,
                                                   float* x, u16* __restrict__ hb,
                                                   const void* means) {
    __shared__ u16 sWa[128 * 136];
    __shared__ u16 sWb[128 * 136];
    __shared__ u16 sW1[128 * 136];
    __shared__ u16 sA[4][16 * 136];
    __shared__ float sBv[128];
    int tid = threadIdx.x;
    int bf = bfflag(means);
    stage_w16(W, 0,   256, sWa, tid, 256, bf);
    stage_w16(W, 128, 256, sWb, tid, 256, bf);
    stage_w16(W1, 0, H, sW1, tid, 256, bf);
    if (tid < 128) sBv[tid] = ldf(B, tid, bf);
    __syncthreads();
    int w = tid >> 6, lane = tid & 63;
    int quad = lane >> 4, l16 = lane & 15;
    u16* myA = sA[w];
    u32* myA32 = (u32*)myA;
    for (int tile = blockIdx.x * 4 + w; tile < NATOMS / 16; tile += gridDim.x * 4) {
        int abase = tile * 16;
        const u32* i0 = in0b + (size_t)abase * 64;
        const u32* i1 = in1 + (size_t)abase * 64;
        #pragma unroll 4
        for (int j = 0; j < 16; ++j)
            myA32[j * 68 + lane] = i0[j * 64 + lane];
        __asm__ volatile("s_waitcnt lgkmcnt(0)" ::: "memory");
        short8 af0 = *(const short8*)&myA[l16 * 136 +   0 + quad * 8];
        short8 af1 = *(const short8*)&myA[l16 * 136 +  32 + quad * 8];
        short8 af2 = *(const short8*)&myA[l16 * 136 +  64 + quad * 8];
        short8 af3 = *(const short8*)&myA[l16 * 136 +  96 + quad * 8];
        #pragma unroll 4
        for (int j = 0; j < 16; ++j)
            myA32[j * 68 + lane] = i1[j * 64 + lane];
        __asm__ volatile("s_waitcnt lgkmcnt(0)" ::: "memory");
        short8 ag0 = *(const short8*)&myA[l16 * 136 +   0 + quad * 8];
        short8 ag1 = *(const short8*)&myA[l16 * 136 +  32 + quad * 8];
        short8 ag2 = *(const short8*)&myA[l16 * 136 +  64 + quad * 8];
        short8 ag3 = *(const short8*)&myA[l16 * 136 +  96 + quad * 8];
        #pragma unroll 1
        for (int nt = 0; nt < 8; ++nt) {
            const u16* wra = &sWa[(nt * 16 + l16) * 136];
            const u16* wrb = &sWb[(nt * 16 + l16) * 136];
            int col = nt * 16 + l16;
            float bias = sBv[col];
            float4v acc = {bias, bias, bias, bias};
            acc = __builtin_amdgcn_mfma_f32_16x16x32_bf16(af0, *(const short8*)&wra[0  + quad * 8], acc, 0, 0, 0);
            acc = __builtin_amdgcn_mfma_f32_16x16x32_bf16(af1, *(const short8*)&wra[32 + quad * 8], acc, 0, 0, 0);
            acc = __builtin_amdgcn_mfma_f32_16x16x32_bf16(af2, *(const short8*)&wra[64 + quad * 8], acc, 0, 0, 0);
            acc = __builtin_amdgcn_mfma_f32_16x16x32_bf16(af3, *(const short8*)&wra[96 + quad * 8], acc, 0, 0, 0);
            acc = __builtin_amdgcn_mfma_f32_16x16x32_bf16(ag0, *(const short8*)&wrb[0  + quad * 8], acc, 0, 0, 0);
            acc = __builtin_amdgcn_mfma_f32_16x16x32_bf16(ag1, *(const short8*)&wrb[32 + quad * 8], acc, 0, 0, 0);
            acc = __builtin_amdgcn_mfma_f32_16x16x32_bf16(ag2, *(const short8*)&wrb[64 + quad * 8], acc, 0, 0, 0);
            acc = __builtin_amdgcn_mfma_f32_16x16x32_bf16(ag3, *(const short8*)&wrb[96 + quad * 8], acc, 0, 0, 0);
            #pragma unroll
            for (int r = 0; r < 4; ++r) {
                x[(size_t)(abase + quad * 4 + r) * H + col] = acc[r];
                myA[(quad * 4 + r) * 136 + col] = bf16r(acc[r]);
            }
        }
        // fused layer-0 lin1: hb = bf16(x @ l1w0.T)
        __asm__ volatile("s_waitcnt lgkmcnt(0)" ::: "memory");
        short8 h0 = *(const short8*)&myA[l16 * 136 +   0 + quad * 8];
        short8 h1 = *(const short8*)&myA[l16 * 136 +  32 + quad * 8];
        short8 h2 = *(const short8*)&myA[l16 * 136 +  64 + quad * 8];
        short8 h3 = *(const short8*)&myA[l16 * 136 +  96 + quad * 8];
        #pragma unroll 1
        for (int nt = 0; nt < 8; ++nt) {
            const u16* wrow = &sW1[(nt * 16 + l16) * 136];
            short8 b0 = *(const short8*)&wrow[0  + quad * 8];
            short8 b1 = *(const short8*)&wrow[32 + quad * 8];
            short8 b2 = *(const short8*)&wrow[64 + quad * 8];
            short8 b3 = *(const short8*)&wrow[96 + quad * 8];
            float4v acc = {0.f, 0.f, 0.f, 0.f};
            acc = __builtin_amdgcn_mfma_f32_16x16x32_bf16(h0, b0, acc, 0, 0, 0);
            acc = __builtin_amdgcn_mfma_f32_16x16x32_bf16(h1, b1, acc, 0, 0, 0);
            acc = __builtin_amdgcn_mfma_f32_16x16x32_bf16(h2, b2, acc, 0, 0, 0);
            acc = __builtin_amdgcn_mfma_f32_16x16x32_bf16(h3, b3, acc, 0, 0, 0);
            int col = nt * 16 + l16;
            hb[(size_t)(abase + quad * 4 + 0) * H + col] = bf16r(acc[0]);
            hb[(size_t)(abase + quad * 4 + 1) * H + col] = bf16r(acc[1]);
            hb[(size_t)(abase + quad * 4 + 2) * H + col] = bf16r(acc[2]);
            hb[(size_t)(abase + quad * 4 + 3) * H + col] = bf16r(acc[3]);
        }
    }
}

// ---- R27 merged: blocks 0-511 = 4 tables (R25 NT=2048 form), blocks 512-824
//      = CSR scatter (R21 form). Both need only rs/cnt (previous kernels). ----
__global__ __launch_bounds__(1024) void k_ft4_scatter(const void* means, const void* betas,
                                                      const void* W0s, const void* B0s,
                                                      const void* W1s, const void* B1s,
                                                      const void* Wne, const void* Bne,
                                                      u16* __restrict__ ftT,
                                                      u16* __restrict__ Tne,
                                                      const int* __restrict__ src,
                                                      const int* __restrict__ dst,
                                                      const void* ew,
                                                      const int* __restrict__ rs,
                                                      int* __restrict__ cnt,
                                                      uint2* __restrict__ ed) {
    int tid = threadIdx.x;
    int bf = bfflag(means);
    if (blockIdx.x >= 512) {   // scatter: build CSR edge data
        int e = (blockIdx.x - 512) * 1024 + tid;
        if (e < NEDGES) {
            int s = src[e];
            int p = rs[s] + atomicAdd(&cnt[s], 1);
            float u = ldf(ew, e, bf) * ((float)(NT - 1) / 5.0f);   // pre-scaled
            ed[p] = make_uint2((u32)dst[e], __float_as_uint(u));
        }
        return;
    }
    __shared__ float sW0[H * 53];
    __shared__ u16 sW1b[128 * 136];
    __shared__ u16 sA16[16 * 136];
    __shared__ float sR[16][56];
    __shared__ float sM[NRBF], sBe[NRBF], sB1v[128], sC[16];
    int t = blockIdx.x >> 7;                 // 0..2 = layer filter, 3 = NE table
    int bb = blockIdx.x & 127;               // 128 blocks per table (NT/16)
    int ne = (t == 3);
    const void* W0 = ne ? Wne : W0s;
    int w0off = ne ? 0 : t * H * NRBF;
    u16* T = ne ? Tne : (ftT + (size_t)t * NT * H);
    if (!ne) stage_w16(W1s, t * H * H, H, sW1b, tid, 1024, bf);
    for (int i = tid; i < H * NRBF; i += 1024) {
        int f2 = i / NRBF, k = i - f2 * NRBF;
        sW0[f2 * 53 + k] = ldf(W0, w0off + i, bf);
    }
    if (tid < NRBF) { sM[tid] = ldf(means, tid, bf); sBe[tid] = ldf(betas, tid, bf); }
    if (tid < 128) sB1v[tid] = ne ? 0.f : ldf(B1s, t * H + tid, bf);
    __syncthreads();
    int g = tid >> 7, f = tid & 127;
    float b0r = ne ? ldf(Bne, f, bf) : ldf(B0s, t * H + f, bf);
    int base = bb * 16;
    int n0 = base + 2 * g, n1 = n0 + 1;
    float wv0 = (float)n0 * (5.0f / (NT - 1));
    float wv1 = (float)n1 * (5.0f / (NT - 1));
    if (f < NRBF) {
        float tt = expf(-wv0) - sM[f];
        sR[2 * g][f] = expf(-sBe[f] * tt * tt);
    } else if (f >= 64 && f < 64 + NRBF) {
        float tt = expf(-wv1) - sM[f - 64];
        sR[2 * g + 1][f - 64] = expf(-sBe[f - 64] * tt * tt);
    }
    __syncthreads();
    float c0 = 0.5f * (cosf(wv0 * 0.62831853071795864f) + 1.f); if (!(wv0 < 5.f)) c0 = 0.f;
    float c1 = 0.5f * (cosf(wv1 * 0.62831853071795864f) + 1.f); if (!(wv1 < 5.f)) c1 = 0.f;
    if (f == 0) { sC[2 * g] = c0; sC[2 * g + 1] = c1; }
    float s0 = 0.f, s1 = 0.f;
    #pragma unroll
    for (int k = 0; k < NRBF; ++k) {
        float wk = sW0[f * 53 + k];
        s0 = fmaf(wk, sR[2 * g][k], s0);
        s1 = fmaf(wk, sR[2 * g + 1][k], s1);
    }
    if (ne) {   // NE table: T = (c*acc + b)*c — block-uniform branch, safe return
        T[(size_t)n0 * H + f] = bf16r(fmaf(c0, s0, b0r) * c0);
        T[(size_t)n1 * H + f] = bf16r(fmaf(c1, s1, b0r) * c1);
        return;
    }
    sA16[(2 * g) * 136 + f]     = bf16r(silu_f(fmaf(c0, s0, b0r)));
    sA16[(2 * g + 1) * 136 + f] = bf16r(silu_f(fmaf(c1, s1, b0r)));
    __syncthreads();
    int w = tid >> 6;
    if (w < 8) {
        int lane = tid & 63;
        int quad = lane >> 4, l16 = lane & 15;
        short8 a0 = *(const short8*)&sA16[l16 * 136 +   0 + quad * 8];
        short8 a1 = *(const short8*)&sA16[l16 * 136 +  32 + quad * 8];
        short8 a2 = *(const short8*)&sA16[l16 * 136 +  64 + quad * 8];
        short8 a3 = *(const short8*)&sA16[l16 * 136 +  96 + quad * 8];
        const u16* wrow = &sW1b[(w * 16 + l16) * 136];
        short8 b0 = *(const short8*)&wrow[0  + quad * 8];
        short8 b1 = *(const short8*)&wrow[32 + quad * 8];
        short8 b2 = *(const short8*)&wrow[64 + quad * 8];
        short8 b3 = *(const short8*)&wrow[96 + quad * 8];
        float4v acc = {0.f, 0.f, 0.f, 0.f};
        acc = __builtin_amdgcn_mfma_f32_16x16x32_bf16(a0, b0, acc, 0, 0, 0);
        acc = __builtin_amdgcn_mfma_f32_16x16x32_bf16(a1, b1, acc, 0, 0, 0);
        acc = __builtin_amdgcn_mfma_f32_16x16x32_bf16(a2, b2, acc, 0, 0, 0);
        acc = __builtin_amdgcn_mfma_f32_16x16x32_bf16(a3, b3, acc, 0, 0, 0);
        int col = w * 16 + l16;
        float bias = sB1v[col];
        #pragma unroll
        for (int r = 0; r < 4; ++r) {
            int row = quad * 4 + r;
            T[(size_t)(base + row) * H + col] = bf16r((acc[r] + bias) * sC[row]);
        }
    }
}

// ---- R21: GATHER edge aggregation — one wave per atom, CSR walk, zero atomics.
#define GEV(i) \
    uint2 ed##i = ed[e + i]; \
    int d##i = (int)ed##i.x; float u##i = __uint_as_float(ed##i.y); \
    int ix##i = min((int)u##i, NT - 2); float fr##i = u##i - (float)ix##i; \
    u32 ta##i = Tb[ix##i * 64 + lane], tb##i = Tb[ix##i * 64 + 64 + lane]; \
    u32 h##i = vh[d##i * 64 + lane]; \
    float vx##i = fmaf(fr##i, bfu((u16)(tb##i & 0xffff)) - bfu((u16)(ta##i & 0xffff)), bfu((u16)(ta##i & 0xffff))) * bfu((u16)(h##i & 0xffff)); \
    float vy##i = fmaf(fr##i, bfu((u16)(tb##i >> 16))    - bfu((u16)(ta##i >> 16)),    bfu((u16)(ta##i >> 16)))    * bfu((u16)(h##i >> 16));
#define GACC(i) \
    if (!(mask_self && d##i == s)) { rx += vx##i; ry += vy##i; }

__global__ __launch_bounds__(256) void k_edge_gather(const int* __restrict__ rs,
                                                     const uint2* __restrict__ ed,
                                                     const u32* __restrict__ Tb,
                                                     const u32* __restrict__ vh,
                                                     u32* __restrict__ accb,
                                                     int mask_self) {
    int tid = threadIdx.x;
    int g = tid >> 6, lane = tid & 63;
    int s = blockIdx.x * 4 + g;          // 2500 blocks x 4 waves = 10000 atoms
    if (s >= NATOMS) return;
    int e0 = rs[s];
    int e1 = (s < NATOMS - 1) ? rs[s + 1] : NEDGES;
    float rx = 0.f, ry = 0.f;
    int e = e0;
    for (; e + 8 <= e1; e += 8) {
        GEV(0) GEV(1) GEV(2) GEV(3) GEV(4) GEV(5) GEV(6) GEV(7)
        GACC(0) GACC(1) GACC(2) GACC(3) GACC(4) GACC(5) GACC(6) GACC(7)
    }
    for (; e < e1; ++e) {
        uint2 edt = ed[e];
        int dt = (int)edt.x; float ut = __uint_as_float(edt.y);
        int ixt = min((int)ut, NT - 2); float frt = ut - (float)ixt;
        u32 tat = Tb[ixt * 64 + lane], tbt = Tb[ixt * 64 + 64 + lane];
        u32 ht = vh[dt * 64 + lane];
        float vxt = fmaf(frt, bfu((u16)(tbt & 0xffff)) - bfu((u16)(tat & 0xffff)), bfu((u16)(tat & 0xffff))) * bfu((u16)(ht & 0xffff));
        float vyt = fmaf(frt, bfu((u16)(tbt >> 16))    - bfu((u16)(tat >> 16)),    bfu((u16)(tat >> 16)))    * bfu((u16)(ht >> 16));
        if (!(mask_self && dt == s)) { rx += vxt; ry += vyt; }
    }
    accb[(size_t)s * 64 + lane] = (u32)bf16r(rx) | ((u32)bf16r(ry) << 16);
}

extern "C" void kernel_launch(void* const* d_in, const int* in_sizes, int n_in,
                              void* d_out, int out_size, void* d_ws, size_t ws_size,
                              hipStream_t stream) {
    const int* z  = (const int*)d_in[0];
    const int* ei = (const int*)d_in[1];
    const void* ew        = d_in[2];
    const void* emb       = d_in[3];
    const void* means     = d_in[4];
    const void* betas     = d_in[5];
    const void* ne_proj_w = d_in[6];
    const void* ne_proj_b = d_in[7];
    const void* ne_comb_w = d_in[8];
    const void* ne_comb_b = d_in[9];
    const void* mlp_w0    = d_in[10];
    const void* mlp_b0    = d_in[11];
    const void* mlp_w1    = d_in[12];
    const void* mlp_b1    = d_in[13];
    const void* lin1_w    = d_in[14];
    const void* lin2_w    = d_in[15];
    const void* lin2_b    = d_in[16];
    const void* lin_w     = d_in[17];
    const void* lin_b     = d_in[18];

    const int* srcp = ei;
    const int* dstp = ei + NEDGES;

    float* x    = (float*)d_ws;            // persistent fp32 node state
    u32*   accb = (u32*)(x + NELEM);       // bf16x2 gather accumulator (NELEM/2 u32)
    int*   deg  = (int*)(accb + NELEM / 2);// deg[10240] + cnt[10240]
    int*   cnt  = deg + 10240;
    int*   rs   = cnt + 10240;
    uint2* ed   = (uint2*)(rs + 10240);    // CSR edge data {dst, ew bits}
    u16*   Tb   = (u16*)(ed + NEDGES);     // NE table, NT x 128 bf16 (0.5MB)
    u16*   hb   = Tb + NT * H;             // bf16 h / x0 mirror
    u16*   ftT  = hb + NELEM;              // 3 filter tables (3 x 0.5MB)

    const int gEdge = (NEDGES + 255) / 256;

    // zero deg+cnt (capture-legal fill node)
    hipMemsetAsync(deg, 0, 20480 * sizeof(int), stream);

    // counting sort histogram
    k_hist<<<gEdge, 256, 0, stream>>>(srcp, deg);

    // embed (blocks 0-312, bf16 mirror only) || scan (block 313)
    k_embed_scan<<<314, 1024, 0, stream>>>(z, emb, means, hb, deg, rs);

    // 4 tables (blocks 0-511) || CSR scatter (blocks 512-824)
    k_ft4_scatter<<<825, 1024, 0, stream>>>(means, betas, mlp_w0, mlp_b0,
                                            mlp_w1, mlp_b1, ne_proj_w, ne_proj_b,
                                            ftT, Tb, srcp, dstp, ew, rs, cnt, ed);

    // NeighborEmbedding edge pass (gather, no atomics)
    k_edge_gather<<<2500, 256, 0, stream>>>(rs, ed, (const u32*)Tb,
                                            (const u32*)hb, accb, 1);
    // combine + fused layer-0 lin1 (reads hb raw for x0; writes x and hb)
    k_mfma_comb<<<256, 256, 0, stream>>>((const u32*)hb, accb, ne_comb_w, ne_comb_b,
                                         lin1_w, x, hb, means);

    for (int L = 0; L < 3; ++L) {
        k_edge_gather<<<2500, 256, 0, stream>>>(rs, ed,
                                                (const u32*)(ftT + (size_t)L * NT * H),
                                                (const u32*)hb, accb, 0);
        // x += silu(a@l2w.T+b2)@lw.T + lb ; fused next-layer lin1 -> hb;
        // last layer writes d_out
        k_mfma_lin<<<256, 256, 0, stream>>>(accb, lin2_w, L * H * H, lin2_b, L * H,
                                            lin_w, L * H * H, lin_b, L * H,
                                            (L < 2) ? lin1_w : nullptr, (L + 1) * H * H,
                                            x, hb, means,
                                            (L == 2) ? d_out : nullptr);
    }
}